// Round 5
// baseline (6741.901 us; speedup 1.0000x reference)
//
#include <hip/hip_runtime.h>

typedef short   bf16x8 __attribute__((ext_vector_type(8)));
typedef unsigned short u16x4 __attribute__((ext_vector_type(4)));
typedef unsigned short u16x8 __attribute__((ext_vector_type(8)));
typedef float   f32x16 __attribute__((ext_vector_type(16)));

constexpr int NSUB  = 8;
constexpr int NCODE = 256;
constexpr int SDIM  = 96;
constexpr int EMB   = NSUB * SDIM;          // 768
constexpr int TILE_ROWS = 128;
constexpr int ROWS_PER_BLK = 1024;
constexpr int NTILES = ROWS_PER_BLK / TILE_ROWS;   // 8
constexpr float C_SHIFT = 192.0f;   // positivity shift (score >= -0.5||x||^2, ||x||^2 << 384)
constexpr float THR = 0.05f;        // recheck trigger >> 2*(key-trunc 0.008 + mfma 0.001)

constexpr int    CB_UNITS      = 8 * 6 * 2 * 64;                 // 6144 x 16B per subspace
constexpr size_t WS_FRAG_BYTES = (size_t)NSUB * CB_UNITS * 16;   // 786432
constexpr size_t WS_NEEDED     = WS_FRAG_BYTES + (size_t)NSUB * NCODE * 4;

__device__ __forceinline__ unsigned short f2bf(float v) {
    unsigned u = __builtin_bit_cast(unsigned, v);
    u = u + 0x7FFFu + ((u >> 16) & 1u);          // RNE
    return (unsigned short)(u >> 16);
}
__device__ __forceinline__ float bf2f(unsigned short h) {
    unsigned u = ((unsigned)h) << 16;
    return __builtin_bit_cast(float, u);
}
__device__ __forceinline__ unsigned umin2(unsigned a, unsigned b) { return a < b ? a : b; }
__device__ __forceinline__ unsigned umax2(unsigned a, unsigned b) { return a > b ? a : b; }

// X LDS swizzle: unit u (1 KiB), byte off in [0,1024): XOR bits 4..6 by (u&7).
// Reads (uniform u per instr) stay conflict-free; writes spread across banks.
__device__ __forceinline__ int xaddr(int u, int off) {
    return u * 1024 + (off ^ ((u & 7) << 4));
}

// ---------------- pre-kernel: pack codebook into ws ----------------
// frag unit u = ((t*6+s)*2+h)*64 + l : code=t*32+(l&31), k0=s*16+(l>>5)*8,
// value = h==0 ? hi : lo of (-cb). wsc2 = 0.5*||c||^2 + C_SHIFT (fp64).
__global__ __launch_bounds__(256) void pq_prep(const float* __restrict__ cb,
                                               unsigned short* __restrict__ wsf,
                                               float* __restrict__ wsc2)
{
    const int m   = (int)blockIdx.x;
    const int tid = (int)threadIdx.x;
    {
        const float* c = cb + ((size_t)m * NCODE + tid) * SDIM;
        double s = 0.0;
        for (int k = 0; k < SDIM; ++k) { double v = (double)c[k]; s += v * v; }
        wsc2[m * NCODE + tid] = (float)(0.5 * s + (double)C_SHIFT);
    }
    for (int i = 0; i < 24; ++i) {
        int u  = i * 256 + tid;
        int l  = u & 63;
        int c6 = u >> 6;
        int h  = c6 & 1; c6 >>= 1;
        int s  = c6 % 6;
        int t  = c6 / 6;
        int code = t * 32 + (l & 31);
        int k0   = s * 16 + (l >> 5) * 8;
        const float* src = cb + (size_t)m * NCODE * SDIM + (size_t)code * SDIM + k0;
        u16x8 o;
        #pragma unroll
        for (int j = 0; j < 8; ++j) {
            float v = -src[j];
            unsigned short hb = f2bf(v);
            o[j] = (h == 0) ? hb : f2bf(v - bf2f(hb));
        }
        *(u16x8*)(wsf + ((size_t)m * CB_UNITS + u) * 8) = o;
    }
}

// ------ main kernel: 8 waves, 32 codes/wave in 48 VGPRs, x streamed via LDS ------
__global__ __launch_bounds__(512, 1) void pq_mfma3(
    const float* __restrict__ emb,
    const float* __restrict__ cb,
    const unsigned short* __restrict__ wsf,
    const float* __restrict__ wsc2,
    float* __restrict__ out,
    int nrows)
{
    __shared__ char  xbuf[48 * 1024];           // 48 units x 1KiB, swizzled
    __shared__ uint2 mergebuf[8 * TILE_ROWS];   // 8 KB
    __shared__ int   trig_cnt;
    __shared__ int   trig_rows[TILE_ROWS];

    const int tid  = (int)threadIdx.x;
    const int w    = tid >> 6;                  // wave 0..7 = code t-group
    const int lane = tid & 63;
    const int m    = (int)(blockIdx.x & 7);
    const int rb   = (int)(blockIdx.x >> 3);
    const int row0 = rb * ROWS_PER_BLK;
    const int hib  = lane >> 5;

    // ---- prologue: this wave's 32-code fragments into 48 VGPRs ----
    bf16x8 cbh[6], cbl[6];
    {
        const unsigned short* wb = wsf + (size_t)m * CB_UNITS * 8;
        #pragma unroll
        for (int s = 0; s < 6; ++s) {
            cbh[s] = *(const bf16x8*)(wb + (size_t)(((w * 6 + s) * 2 + 0) * 64 + lane) * 8);
            cbl[s] = *(const bf16x8*)(wb + (size_t)(((w * 6 + s) * 2 + 1) * 64 + lane) * 8);
        }
    }
    // ---- 0.5||c||^2 + shift for this wave's 16 acc slots (persistent) ----
    f32x16 c2r;
    {
        const float* c2p = wsc2 + m * NCODE + w * 32 + hib * 4;
        #pragma unroll
        for (int rq = 0; rq < 4; ++rq) {
            float4 q = *(const float4*)(c2p + rq * 8);
            c2r[rq*4+0] = q.x; c2r[rq*4+1] = q.y;
            c2r[rq*4+2] = q.z; c2r[rq*4+3] = q.w;
        }
    }

    float4 xf[6];
    auto issue_x = [&](int t) {
        #pragma unroll
        for (int ii = 0; ii < 6; ++ii) {
            int Q = ii * 512 + tid;
            int r = Q / 24, f = Q % 24;
            int gr = row0 + t * TILE_ROWS + r;
            if (gr >= nrows) gr = nrows - 1;
            xf[ii] = *(const float4*)(emb + (size_t)gr * EMB + m * SDIM + f * 4);
        }
    };
    issue_x(0);

    #pragma unroll 1
    for (int it = 0; it < NTILES; ++it) {
        const int rowt0 = row0 + it * TILE_ROWS;

        // ---- P1: convert xf -> bf16 hi/lo fragments in LDS (swizzled) ----
        #pragma unroll
        for (int ii = 0; ii < 6; ++ii) {
            int Q = ii * 512 + tid;
            int r = Q / 24, f = Q % 24;
            int s = f >> 2, kh = (f >> 1) & 1, j0 = f & 1;
            int g = r >> 5, lp = (r & 31) + 32 * kh;
            float v[4] = { xf[ii].x, xf[ii].y, xf[ii].z, xf[ii].w };
            u16x4 hi4, lo4;
            #pragma unroll
            for (int e = 0; e < 4; ++e) {
                unsigned short hb = f2bf(v[e]);
                hi4[e] = hb;
                lo4[e] = f2bf(v[e] - bf2f(hb));
            }
            int uh  = (g * 6 + s) * 2;
            int off = lp * 16 + j0 * 8;
            *(u16x4*)(xbuf + xaddr(uh, off))     = hi4;
            *(u16x4*)(xbuf + xaddr(uh + 1, off)) = lo4;
        }
        __syncthreads();                            // bar_A: X ready, mergebuf free
        if (tid == 0) trig_cnt = 0;

        // ---- P2: MFMA (hh+lh over xh, then hl over xl) + packed-key epilogue ----
        #pragma unroll 1
        for (int g = 0; g < 4; ++g) {
            f32x16 acc = c2r;
            #pragma unroll
            for (int s = 0; s < 6; ++s) {
                bf16x8 xh = *(const bf16x8*)(xbuf + xaddr((g * 6 + s) * 2, lane * 16));
                acc = __builtin_amdgcn_mfma_f32_32x32x16_bf16(cbh[s], xh, acc, 0, 0, 0);
                acc = __builtin_amdgcn_mfma_f32_32x32x16_bf16(cbl[s], xh, acc, 0, 0, 0);
            }
            #pragma unroll
            for (int s = 0; s < 6; ++s) {
                bf16x8 xl = *(const bf16x8*)(xbuf + xaddr((g * 6 + s) * 2 + 1, lane * 16));
                acc = __builtin_amdgcn_mfma_f32_32x32x16_bf16(cbh[s], xl, acc, 0, 0, 0);
            }
            // packed keys: (score-bits & ~0xFF) | code — positive floats sort as uints
            unsigned m1 = ~0u, m2 = ~0u;
            #pragma unroll
            for (int rq = 0; rq < 4; ++rq) {
                #pragma unroll
                for (int rr = 0; rr < 4; ++rr) {
                    unsigned idx = (unsigned)(w * 32 + rq * 8 + hib * 4 + rr);
                    unsigned kb  = (__builtin_bit_cast(unsigned, acc[rq*4+rr]) & 0xFFFFFF00u) | idx;
                    unsigned mx  = umax2(m1, kb);
                    m2 = umin2(m2, mx); m1 = umin2(m1, kb);
                }
            }
            unsigned om1 = (unsigned)__shfl_xor((int)m1, 32);
            unsigned om2 = (unsigned)__shfl_xor((int)m2, 32);
            unsigned mm1 = umin2(m1, om1);
            unsigned mm2 = umin2(umax2(m1, om1), umin2(m2, om2));
            if (lane < 32)
                mergebuf[w * TILE_ROWS + g * 32 + lane] = uint2{ mm1, mm2 };
        }
        __syncthreads();                            // bar_B: mergebuf ready, X consumed

        // ---- P3: issue next x; merge 8 waves; write non-triggered rows ----
        if (it + 1 < NTILES) issue_x(it + 1);
        {
            int r = tid >> 2, q = tid & 3;          // 4 threads per row
            int grow = rowt0 + r;
            if (grow < nrows) {
                unsigned a1 = ~0u, a2 = ~0u;
                #pragma unroll
                for (int wv = 0; wv < 8; ++wv) {
                    uint2 p = mergebuf[wv * TILE_ROWS + r];
                    unsigned n1 = umin2(a1, p.x);
                    a2 = umin2(umax2(a1, p.x), umin2(a2, p.y));
                    a1 = n1;
                }
                float s1 = __builtin_bit_cast(float, a1 & 0xFFFFFF00u);
                float s2 = __builtin_bit_cast(float, a2 & 0xFFFFFF00u);
                int   k  = (int)(a1 & 0xFFu);
                if (s2 - s1 < THR) {
                    if (q == 0) { int p = atomicAdd(&trig_cnt, 1); trig_rows[p] = r; }
                } else {
                    const float* src = cb + ((size_t)m * NCODE + k) * SDIM + q * 24;
                    float* dst = out + (size_t)grow * EMB + m * SDIM + q * 24;
                    #pragma unroll
                    for (int ii = 0; ii < 6; ++ii)
                        *(float4*)(dst + ii * 4) = *(const float4*)(src + ii * 4);
                }
            }
        }
        __syncthreads();                            // bar_C: trig list final

        // ---- P4: exact fp64 rescan for triggered rows (one wave per row, rare) ----
        {
            int nt = trig_cnt;
            for (int j = w; j < nt; j += 8) {
                int r = trig_rows[j];
                int grow = rowt0 + r;
                const float* xr = emb + (size_t)grow * EMB + m * SDIM;
                double bd = 1e300; int bc = NCODE;
                #pragma unroll 1
                for (int qc = 0; qc < 4; ++qc) {
                    int code = qc * 64 + lane;
                    const float* cv = cb + ((size_t)m * NCODE + code) * SDIM;
                    double acc = 0.0;
                    #pragma unroll
                    for (int kk = 0; kk < SDIM; kk += 4) {
                        float4 xv = *(const float4*)(xr + kk);
                        float4 cc = *(const float4*)(cv + kk);
                        double d0 = (double)xv.x - (double)cc.x;
                        double d1 = (double)xv.y - (double)cc.y;
                        double d2 = (double)xv.z - (double)cc.z;
                        double d3 = (double)xv.w - (double)cc.w;
                        acc += d0*d0 + d1*d1 + d2*d2 + d3*d3;
                    }
                    if (acc < bd) { bd = acc; bc = code; }   // qc ascending: first-min kept
                }
                #pragma unroll
                for (int off = 32; off > 0; off >>= 1) {
                    double od = __shfl_xor(bd, off);
                    int    oc = __shfl_xor(bc, off);
                    if (od < bd || (od == bd && oc < bc)) { bd = od; bc = oc; }
                }
                if (lane < 24) {
                    float4 v = *(const float4*)(cb + ((size_t)m * NCODE + bc) * SDIM + lane * 4);
                    *(float4*)(out + (size_t)grow * EMB + m * SDIM + lane * 4) = v;
                }
            }
        }
        // next P1 only touches xbuf (last read pre-bar_B); bar_A fences reuse
    }
}

// ---------------- fallback (round-2 kernel, validated) ----------------
__global__ __launch_bounds__(256) void pq_argmin_kernel(
    const float* __restrict__ emb, const float* __restrict__ cb,
    float* __restrict__ out, int nrows)
{
    const int m   = (int)(blockIdx.x & 7);
    const int row = (int)(blockIdx.x >> 3) * 256 + (int)threadIdx.x;
    const float* __restrict__ cbm = cb + (size_t)m * (NCODE * SDIM);
    __shared__ float half_c2[NCODE];
    {
        const int k = (int)threadIdx.x;
        const float* c = cbm + k * SDIM;
        float s = 0.f;
        #pragma unroll
        for (int i = 0; i < SDIM; i += 4) {
            const float4 v = *reinterpret_cast<const float4*>(c + i);
            s = fmaf(v.x, v.x, s); s = fmaf(v.y, v.y, s);
            s = fmaf(v.z, v.z, s); s = fmaf(v.w, v.w, s);
        }
        half_c2[k] = 0.5f * s;
    }
    __syncthreads();
    if (row >= nrows) return;
    float x[SDIM];
    {
        const float* xr = emb + (size_t)row * EMB + m * SDIM;
        #pragma unroll
        for (int i = 0; i < SDIM; i += 4) {
            const float4 v = *reinterpret_cast<const float4*>(xr + i);
            x[i+0] = v.x; x[i+1] = v.y; x[i+2] = v.z; x[i+3] = v.w;
        }
    }
    float best = 3.4e38f, best2 = 3.4e38f;
    int bestk = 0, bestk2 = 0;
    #pragma unroll 1
    for (int k = 0; k < NCODE; k += 4) {
        const float* c0 = cbm + (k + 0) * SDIM;
        const float* c1 = cbm + (k + 1) * SDIM;
        const float* c2 = cbm + (k + 2) * SDIM;
        const float* c3 = cbm + (k + 3) * SDIM;
        float a0 = 0.f, a1 = 0.f, a2 = 0.f, a3 = 0.f;
        #pragma unroll
        for (int i = 0; i < SDIM; i += 4) {
            const float4 v0 = *reinterpret_cast<const float4*>(c0 + i);
            const float4 v1 = *reinterpret_cast<const float4*>(c1 + i);
            const float4 v2 = *reinterpret_cast<const float4*>(c2 + i);
            const float4 v3 = *reinterpret_cast<const float4*>(c3 + i);
            a0 = fmaf(x[i+0], v0.x, a0); a0 = fmaf(x[i+1], v0.y, a0);
            a0 = fmaf(x[i+2], v0.z, a0); a0 = fmaf(x[i+3], v0.w, a0);
            a1 = fmaf(x[i+0], v1.x, a1); a1 = fmaf(x[i+1], v1.y, a1);
            a1 = fmaf(x[i+2], v1.z, a1); a1 = fmaf(x[i+3], v1.w, a1);
            a2 = fmaf(x[i+0], v2.x, a2); a2 = fmaf(x[i+1], v2.y, a2);
            a2 = fmaf(x[i+2], v2.z, a2); a2 = fmaf(x[i+3], v2.w, a2);
            a3 = fmaf(x[i+0], v3.x, a3); a3 = fmaf(x[i+1], v3.y, a3);
            a3 = fmaf(x[i+2], v3.z, a3); a3 = fmaf(x[i+3], v3.w, a3);
        }
        const float s[4] = { half_c2[k+0] - a0, half_c2[k+1] - a1,
                             half_c2[k+2] - a2, half_c2[k+3] - a3 };
        #pragma unroll
        for (int j = 0; j < 4; ++j) {
            if (s[j] < best)       { best2 = best; bestk2 = bestk; best = s[j]; bestk = k + j; }
            else if (s[j] < best2) { best2 = s[j]; bestk2 = k + j; }
        }
    }
    if (best2 - best < 0.02f) {
        const float* ca = cbm + bestk  * SDIM;
        const float* cbv = cbm + bestk2 * SDIM;
        double da = 0.0, db = 0.0;
        for (int i = 0; i < SDIM; ++i) {
            const double ea = (double)x[i] - (double)ca[i];
            const double eb = (double)x[i] - (double)cbv[i];
            da += ea * ea; db += eb * eb;
        }
        if (db < da || (db == da && bestk2 < bestk)) bestk = bestk2;
    }
    const float* cbest = cbm + bestk * SDIM;
    float* o = out + (size_t)row * EMB + m * SDIM;
    #pragma unroll
    for (int i = 0; i < SDIM; i += 4)
        *reinterpret_cast<float4*>(o + i) = *reinterpret_cast<const float4*>(cbest + i);
}

extern "C" void kernel_launch(void* const* d_in, const int* in_sizes, int n_in,
                              void* d_out, int out_size, void* d_ws, size_t ws_size,
                              hipStream_t stream) {
    const float* emb = (const float*)d_in[0];
    const float* cb  = (const float*)d_in[1];
    float* out = (float*)d_out;
    const int nrows = in_sizes[0] / EMB;    // 65536

    if (ws_size < WS_NEEDED) {
        const int rowBlocks = (nrows + 255) / 256;
        pq_argmin_kernel<<<dim3(rowBlocks * NSUB), dim3(256), 0, stream>>>(emb, cb, out, nrows);
        return;
    }

    unsigned short* wsf = (unsigned short*)d_ws;
    float* wsc2 = (float*)((char*)d_ws + WS_FRAG_BYTES);

    pq_prep<<<dim3(NSUB), dim3(256), 0, stream>>>(cb, wsf, wsc2);

    const int nb = (nrows + ROWS_PER_BLK - 1) / ROWS_PER_BLK;   // 64
    pq_mfma3<<<dim3(nb * NSUB), dim3(512), 0, stream>>>(emb, cb, wsf, wsc2, out, nrows);
}

// Round 6
// 6066.464 us; speedup vs baseline: 1.1113x; 1.1113x over previous
//
#include <hip/hip_runtime.h>

typedef short   bf16x8 __attribute__((ext_vector_type(8)));
typedef unsigned short u16x4 __attribute__((ext_vector_type(4)));
typedef unsigned short u16x8 __attribute__((ext_vector_type(8)));
typedef float   f32x16 __attribute__((ext_vector_type(16)));

constexpr int NSUB  = 8;
constexpr int NCODE = 256;
constexpr int SDIM  = 96;
constexpr int EMB   = NSUB * SDIM;          // 768
constexpr int TILE_ROWS = 64;
constexpr int ROWS_PER_BLK = 2048;
constexpr int NTILES = ROWS_PER_BLK / TILE_ROWS;   // 32
constexpr float C_SHIFT = 192.0f;   // positivity shift (score >= -0.5||x||^2, ||x||^2 << 384)
constexpr float THR = 0.05f;        // recheck trigger >> 2*(key-trunc 0.008 + mfma 0.001)

constexpr int    CB_UNITS      = 8 * 6 * 2 * 64;                 // 6144 x 16B per subspace
constexpr size_t WS_FRAG_BYTES = (size_t)NSUB * CB_UNITS * 16;   // 786432
constexpr size_t WS_NEEDED     = WS_FRAG_BYTES + (size_t)NSUB * NCODE * 4;

// ---- dynamic LDS layout (bytes) ----
constexpr int CB_OFF    = 0;                        // 98304 : codebook frags (one m)
constexpr int X_OFF     = 98304;                    // 2 x 24576 : x frag double buffer
constexpr int C2_OFF    = X_OFF + 2 * 24576;        // 1024 : 0.5||c||^2 + shift
constexpr int MB_OFF    = C2_OFF + 1024;            // 1024 : mergebuf  [2][64] uint2
constexpr int TC_OFF    = MB_OFF + 1024;            // 16   : trig_cnt[2] (+pad)
constexpr int TR_OFF    = TC_OFF + 16;              // 512  : trig_rows[2][64]
constexpr int LDS_TOTAL = TR_OFF + 512;             // 150400 <= 163840

__device__ __forceinline__ unsigned short f2bf(float v) {
    unsigned u = __builtin_bit_cast(unsigned, v);
    u = u + 0x7FFFu + ((u >> 16) & 1u);          // RNE
    return (unsigned short)(u >> 16);
}
__device__ __forceinline__ float bf2f(unsigned short h) {
    unsigned u = ((unsigned)h) << 16;
    return __builtin_bit_cast(float, u);
}
__device__ __forceinline__ unsigned umin2(unsigned a, unsigned b) { return a < b ? a : b; }
__device__ __forceinline__ unsigned umax2(unsigned a, unsigned b) { return a > b ? a : b; }

// X LDS swizzle: unit u (1 KiB), byte off in [0,1024): XOR bits 4..6 by (u&7).
// Reads (uniform u per instr) stay conflict-free; writes spread across banks.
__device__ __forceinline__ int xaddr(int u, int off) {
    return u * 1024 + (off ^ ((u & 7) << 4));
}

__device__ __forceinline__ void gll16(const void* g, void* lds) {
    __builtin_amdgcn_global_load_lds((const __attribute__((address_space(1))) unsigned int*)g,
                                     (__attribute__((address_space(3))) unsigned int*)lds, 16, 0, 0);
}
__device__ __forceinline__ void gll4(const void* g, void* lds) {
    __builtin_amdgcn_global_load_lds((const __attribute__((address_space(1))) unsigned int*)g,
                                     (__attribute__((address_space(3))) unsigned int*)lds, 4, 0, 0);
}

// ---------------- pre-kernel: pack codebook into ws ----------------
// frag unit u = ((t*6+s)*2+h)*64 + l : code=t*32+(l&31), k0=s*16+(l>>5)*8,
// value = h==0 ? hi : lo of (-cb). wsc2 = 0.5*||c||^2 + C_SHIFT (fp64).
__global__ __launch_bounds__(256) void pq_prep(const float* __restrict__ cb,
                                               unsigned short* __restrict__ wsf,
                                               float* __restrict__ wsc2)
{
    const int m   = (int)blockIdx.x;
    const int tid = (int)threadIdx.x;
    {
        const float* c = cb + ((size_t)m * NCODE + tid) * SDIM;
        double s = 0.0;
        for (int k = 0; k < SDIM; ++k) { double v = (double)c[k]; s += v * v; }
        wsc2[m * NCODE + tid] = (float)(0.5 * s + (double)C_SHIFT);
    }
    for (int i = 0; i < 24; ++i) {
        int u  = i * 256 + tid;
        int l  = u & 63;
        int c6 = u >> 6;
        int h  = c6 & 1; c6 >>= 1;
        int s  = c6 % 6;
        int t  = c6 / 6;
        int code = t * 32 + (l & 31);
        int k0   = s * 16 + (l >> 5) * 8;
        const float* src = cb + (size_t)m * NCODE * SDIM + (size_t)code * SDIM + k0;
        u16x8 o;
        #pragma unroll
        for (int j = 0; j < 8; ++j) {
            float v = -src[j];
            unsigned short hb = f2bf(v);
            o[j] = (h == 0) ? hb : f2bf(v - bf2f(hb));
        }
        *(u16x8*)(wsf + ((size_t)m * CB_UNITS + u) * 8) = o;
    }
}

// ------ main: 256 thr / (256,1) [proven 248-VGPR regime], cb staged ONCE, ------
// ------ x double-buffered; wave = (row-group g, t-half); dual acc chains  ------
__global__ __launch_bounds__(256, 1) void pq_mfma4(
    const float* __restrict__ emb,
    const float* __restrict__ cb,
    const unsigned short* __restrict__ wsf,
    const float* __restrict__ wsc2,
    float* __restrict__ out,
    int nrows)
{
    extern __shared__ char smem[];
    const int tid   = (int)threadIdx.x;
    const int w     = tid >> 6;
    const int lane  = tid & 63;
    const int hib   = lane >> 5;
    const int m     = (int)(blockIdx.x & 7);
    const int chunk = (int)(blockIdx.x >> 3);
    const int row0  = chunk * ROWS_PER_BLK;

    int*  tc = (int*)(smem + TC_OFF);
    int*  tr = (int*)(smem + TR_OFF);
    uint2* mb = (uint2*)(smem + MB_OFF);

    // ---- prologue: stage codebook frags + c2 ONCE (async), load x(t0) ----
    {
        const unsigned short* wb = wsf + (size_t)m * CB_UNITS * 8;
        #pragma unroll
        for (int i = 0; i < 24; ++i) {
            int sb = (w * 24 + i) * 64;
            gll16(wb + (size_t)(sb + lane) * 8, smem + CB_OFF + sb * 16);
        }
        gll4(wsc2 + m * NCODE + w * 64 + lane, smem + C2_OFF + w * 256);
    }

    float4 xf[6];
    auto issue_x = [&](int t) {
        #pragma unroll
        for (int ii = 0; ii < 6; ++ii) {
            int Q = ii * 256 + tid;
            int r = Q / 24, f = Q % 24;
            int gr = row0 + t * TILE_ROWS + r;
            if (gr >= nrows) gr = nrows - 1;
            xf[ii] = *(const float4*)(emb + (size_t)gr * EMB + m * SDIM + f * 4);
        }
    };
    auto convert_x = [&](int p) {
        char* xb = smem + X_OFF + p * 24576;
        #pragma unroll
        for (int ii = 0; ii < 6; ++ii) {
            int Q = ii * 256 + tid;
            int r = Q / 24, f = Q % 24;
            int s = f >> 2, kh = (f >> 1) & 1, j0 = f & 1;
            int g = r >> 5, lp = (r & 31) + 32 * kh;
            float v[4] = { xf[ii].x, xf[ii].y, xf[ii].z, xf[ii].w };
            u16x4 hi4, lo4;
            #pragma unroll
            for (int e = 0; e < 4; ++e) {
                unsigned short hb = f2bf(v[e]);
                hi4[e] = hb;
                lo4[e] = f2bf(v[e] - bf2f(hb));
            }
            int uh  = (g * 6 + s) * 2;
            int off = lp * 16 + j0 * 8;
            *(u16x4*)(xb + xaddr(uh, off))     = hi4;
            *(u16x4*)(xb + xaddr(uh + 1, off)) = lo4;
        }
    };

    issue_x(0);
    convert_x(0);
    issue_x(1);
    if (tid == 0) tc[0] = 0;
    __syncthreads();                    // drains gll staging + buf0 writes

    const int g     = w & 1;            // row group (32 rows) this wave computes
    const int thalf = w >> 1;           // code half (4 t-groups) this wave computes
    int p = 0;

    #pragma unroll 1
    for (int t = 0; t < NTILES; ++t) {
        const int rowt0 = row0 + t * TILE_ROWS;

        // ---- P2: x frags to regs; convert next tile; MFMA dual-chain ----
        const char* xb = smem + X_OFF + p * 24576;
        bf16x8 xh[6], xl[6];
        #pragma unroll
        for (int s = 0; s < 6; ++s) {
            xh[s] = *(const bf16x8*)(xb + xaddr((g * 6 + s) * 2,     lane * 16));
            xl[s] = *(const bf16x8*)(xb + xaddr((g * 6 + s) * 2 + 1, lane * 16));
        }
        if (t + 1 < NTILES) convert_x(p ^ 1);   // xf holds tile t+1

        unsigned m1 = ~0u, m2 = ~0u;
        #pragma unroll
        for (int tt = 0; tt < 4; tt += 2) {
            const int t0 = thalf * 4 + tt, t1 = t0 + 1;
            f32x16 a0, a1;
            {
                const float* c2p = (const float*)(smem + C2_OFF);
                #pragma unroll
                for (int rq = 0; rq < 4; ++rq) {
                    float4 q0 = *(const float4*)(c2p + t0 * 32 + rq * 8 + hib * 4);
                    float4 q1 = *(const float4*)(c2p + t1 * 32 + rq * 8 + hib * 4);
                    a0[rq*4+0]=q0.x; a0[rq*4+1]=q0.y; a0[rq*4+2]=q0.z; a0[rq*4+3]=q0.w;
                    a1[rq*4+0]=q1.x; a1[rq*4+1]=q1.y; a1[rq*4+2]=q1.z; a1[rq*4+3]=q1.w;
                }
            }
            #pragma unroll
            for (int s = 0; s < 6; ++s) {
                const char* cbp = smem + CB_OFF;
                bf16x8 ah0 = *(const bf16x8*)(cbp + (((t0 * 6 + s) * 2 + 0) * 64 + lane) * 16);
                bf16x8 al0 = *(const bf16x8*)(cbp + (((t0 * 6 + s) * 2 + 1) * 64 + lane) * 16);
                bf16x8 ah1 = *(const bf16x8*)(cbp + (((t1 * 6 + s) * 2 + 0) * 64 + lane) * 16);
                bf16x8 al1 = *(const bf16x8*)(cbp + (((t1 * 6 + s) * 2 + 1) * 64 + lane) * 16);
                a0 = __builtin_amdgcn_mfma_f32_32x32x16_bf16(ah0, xh[s], a0, 0, 0, 0);
                a1 = __builtin_amdgcn_mfma_f32_32x32x16_bf16(ah1, xh[s], a1, 0, 0, 0);
                a0 = __builtin_amdgcn_mfma_f32_32x32x16_bf16(al0, xh[s], a0, 0, 0, 0);
                a1 = __builtin_amdgcn_mfma_f32_32x32x16_bf16(al1, xh[s], a1, 0, 0, 0);
                a0 = __builtin_amdgcn_mfma_f32_32x32x16_bf16(ah0, xl[s], a0, 0, 0, 0);
                a1 = __builtin_amdgcn_mfma_f32_32x32x16_bf16(ah1, xl[s], a1, 0, 0, 0);
            }
            // packed keys: (score-bits & ~0xFF) | code — positive floats sort as uints
            #pragma unroll
            for (int rq = 0; rq < 4; ++rq) {
                #pragma unroll
                for (int rr = 0; rr < 4; ++rr) {
                    unsigned i0 = (unsigned)(t0 * 32 + rq * 8 + hib * 4 + rr);
                    unsigned k0 = (__builtin_bit_cast(unsigned, a0[rq*4+rr]) & 0xFFFFFF00u) | i0;
                    unsigned x0 = umax2(m1, k0);
                    m2 = umin2(m2, x0); m1 = umin2(m1, k0);
                    unsigned i1 = (unsigned)(t1 * 32 + rq * 8 + hib * 4 + rr);
                    unsigned k1 = (__builtin_bit_cast(unsigned, a1[rq*4+rr]) & 0xFFFFFF00u) | i1;
                    unsigned x1 = umax2(m1, k1);
                    m2 = umin2(m2, x1); m1 = umin2(m1, k1);
                }
            }
        }
        {
            unsigned om1 = (unsigned)__shfl_xor((int)m1, 32);
            unsigned om2 = (unsigned)__shfl_xor((int)m2, 32);
            unsigned mm1 = umin2(m1, om1);
            unsigned mm2 = umin2(umax2(m1, om1), umin2(m2, om2));
            if (lane < 32)
                mb[thalf * 64 + g * 32 + lane] = uint2{ mm1, mm2 };
        }
        __syncthreads();                            // bar1: mergebuf + next-buf ready

        // ---- P3: prefetch t+2; merge 2 halves; write non-triggered rows ----
        if (t + 2 < NTILES) issue_x(t + 2);
        if (tid == 0) tc[(t + 1) & 1] = 0;
        {
            int r = tid >> 2, q = tid & 3;
            int grow = rowt0 + r;
            if (grow < nrows) {
                uint2 p0 = mb[r];
                uint2 p1 = mb[64 + r];
                unsigned a1k = umin2(p0.x, p1.x);
                unsigned a2k = umin2(umax2(p0.x, p1.x), umin2(p0.y, p1.y));
                float s1 = __builtin_bit_cast(float, a1k & 0xFFFFFF00u);
                float s2 = __builtin_bit_cast(float, a2k & 0xFFFFFF00u);
                int   k  = (int)(a1k & 0xFFu);
                if (s2 - s1 < THR) {
                    if (q == 0) { int pos = atomicAdd(&tc[t & 1], 1); tr[(t & 1) * 64 + pos] = r; }
                } else {
                    const float* src = cb + ((size_t)m * NCODE + k) * SDIM + q * 24;
                    float* dst = out + (size_t)grow * EMB + m * SDIM + q * 24;
                    #pragma unroll
                    for (int ii = 0; ii < 6; ++ii)
                        *(float4*)(dst + ii * 4) = *(const float4*)(src + ii * 4);
                }
            }
        }
        __syncthreads();                            // bar2: trig list final

        // ---- P4: exact fp64 rescan for triggered rows (one wave per row, rare) ----
        {
            int nt = tc[t & 1];
            for (int j = w; j < nt; j += 4) {
                int r = tr[(t & 1) * 64 + j];
                int grow = rowt0 + r;
                const float* xr = emb + (size_t)grow * EMB + m * SDIM;
                double bd = 1e300; int bc = NCODE;
                #pragma unroll 1
                for (int qc = 0; qc < 4; ++qc) {
                    int code = qc * 64 + lane;
                    const float* cv = cb + ((size_t)m * NCODE + code) * SDIM;
                    double acc = 0.0;
                    #pragma unroll
                    for (int kk = 0; kk < SDIM; kk += 4) {
                        float4 xv = *(const float4*)(xr + kk);
                        float4 cc = *(const float4*)(cv + kk);
                        double d0 = (double)xv.x - (double)cc.x;
                        double d1 = (double)xv.y - (double)cc.y;
                        double d2 = (double)xv.z - (double)cc.z;
                        double d3 = (double)xv.w - (double)cc.w;
                        acc += d0*d0 + d1*d1 + d2*d2 + d3*d3;
                    }
                    if (acc < bd) { bd = acc; bc = code; }   // qc ascending: first-min kept
                }
                #pragma unroll
                for (int off = 32; off > 0; off >>= 1) {
                    double od = __shfl_xor(bd, off);
                    int    oc = __shfl_xor(bc, off);
                    if (od < bd || (od == bd && oc < bc)) { bd = od; bc = oc; }
                }
                if (lane < 24) {
                    float4 v = *(const float4*)(cb + ((size_t)m * NCODE + bc) * SDIM + lane * 4);
                    *(float4*)(out + (size_t)grow * EMB + m * SDIM + lane * 4) = v;
                }
            }
        }
        p ^= 1;
        // next P2 reads buf[p] (written pre-bar1) and overwrites buf[p^1]
        // (consumed pre-bar1) — both fenced by bar1+bar2.
    }
}

// ---------------- fallback (round-2 kernel, validated) ----------------
__global__ __launch_bounds__(256) void pq_argmin_kernel(
    const float* __restrict__ emb, const float* __restrict__ cb,
    float* __restrict__ out, int nrows)
{
    const int m   = (int)(blockIdx.x & 7);
    const int row = (int)(blockIdx.x >> 3) * 256 + (int)threadIdx.x;
    const float* __restrict__ cbm = cb + (size_t)m * (NCODE * SDIM);
    __shared__ float half_c2[NCODE];
    {
        const int k = (int)threadIdx.x;
        const float* c = cbm + k * SDIM;
        float s = 0.f;
        #pragma unroll
        for (int i = 0; i < SDIM; i += 4) {
            const float4 v = *reinterpret_cast<const float4*>(c + i);
            s = fmaf(v.x, v.x, s); s = fmaf(v.y, v.y, s);
            s = fmaf(v.z, v.z, s); s = fmaf(v.w, v.w, s);
        }
        half_c2[k] = 0.5f * s;
    }
    __syncthreads();
    if (row >= nrows) return;
    float x[SDIM];
    {
        const float* xr = emb + (size_t)row * EMB + m * SDIM;
        #pragma unroll
        for (int i = 0; i < SDIM; i += 4) {
            const float4 v = *reinterpret_cast<const float4*>(xr + i);
            x[i+0] = v.x; x[i+1] = v.y; x[i+2] = v.z; x[i+3] = v.w;
        }
    }
    float best = 3.4e38f, best2 = 3.4e38f;
    int bestk = 0, bestk2 = 0;
    #pragma unroll 1
    for (int k = 0; k < NCODE; k += 4) {
        const float* c0 = cbm + (k + 0) * SDIM;
        const float* c1 = cbm + (k + 1) * SDIM;
        const float* c2 = cbm + (k + 2) * SDIM;
        const float* c3 = cbm + (k + 3) * SDIM;
        float a0 = 0.f, a1 = 0.f, a2 = 0.f, a3 = 0.f;
        #pragma unroll
        for (int i = 0; i < SDIM; i += 4) {
            const float4 v0 = *reinterpret_cast<const float4*>(c0 + i);
            const float4 v1 = *reinterpret_cast<const float4*>(c1 + i);
            const float4 v2 = *reinterpret_cast<const float4*>(c2 + i);
            const float4 v3 = *reinterpret_cast<const float4*>(c3 + i);
            a0 = fmaf(x[i+0], v0.x, a0); a0 = fmaf(x[i+1], v0.y, a0);
            a0 = fmaf(x[i+2], v0.z, a0); a0 = fmaf(x[i+3], v0.w, a0);
            a1 = fmaf(x[i+0], v1.x, a1); a1 = fmaf(x[i+1], v1.y, a1);
            a1 = fmaf(x[i+2], v1.z, a1); a1 = fmaf(x[i+3], v1.w, a1);
            a2 = fmaf(x[i+0], v2.x, a2); a2 = fmaf(x[i+1], v2.y, a2);
            a2 = fmaf(x[i+2], v2.z, a2); a2 = fmaf(x[i+3], v2.w, a2);
            a3 = fmaf(x[i+0], v3.x, a3); a3 = fmaf(x[i+1], v3.y, a3);
            a3 = fmaf(x[i+2], v3.z, a3); a3 = fmaf(x[i+3], v3.w, a3);
        }
        const float s[4] = { half_c2[k+0] - a0, half_c2[k+1] - a1,
                             half_c2[k+2] - a2, half_c2[k+3] - a3 };
        #pragma unroll
        for (int j = 0; j < 4; ++j) {
            if (s[j] < best)       { best2 = best; bestk2 = bestk; best = s[j]; bestk = k + j; }
            else if (s[j] < best2) { best2 = s[j]; bestk2 = k + j; }
        }
    }
    if (best2 - best < 0.02f) {
        const float* ca = cbm + bestk  * SDIM;
        const float* cbv = cbm + bestk2 * SDIM;
        double da = 0.0, db = 0.0;
        for (int i = 0; i < SDIM; ++i) {
            const double ea = (double)x[i] - (double)ca[i];
            const double eb = (double)x[i] - (double)cbv[i];
            da += ea * ea; db += eb * eb;
        }
        if (db < da || (db == da && bestk2 < bestk)) bestk = bestk2;
    }
    const float* cbest = cbm + bestk * SDIM;
    float* o = out + (size_t)row * EMB + m * SDIM;
    #pragma unroll
    for (int i = 0; i < SDIM; i += 4)
        *reinterpret_cast<float4*>(o + i) = *reinterpret_cast<const float4*>(cbest + i);
}

extern "C" void kernel_launch(void* const* d_in, const int* in_sizes, int n_in,
                              void* d_out, int out_size, void* d_ws, size_t ws_size,
                              hipStream_t stream) {
    const float* emb = (const float*)d_in[0];
    const float* cb  = (const float*)d_in[1];
    float* out = (float*)d_out;
    const int nrows = in_sizes[0] / EMB;    // 65536

    if (ws_size < WS_NEEDED) {
        const int rowBlocks = (nrows + 255) / 256;
        pq_argmin_kernel<<<dim3(rowBlocks * NSUB), dim3(256), 0, stream>>>(emb, cb, out, nrows);
        return;
    }

    unsigned short* wsf = (unsigned short*)d_ws;
    float* wsc2 = (float*)((char*)d_ws + WS_FRAG_BYTES);

    pq_prep<<<dim3(NSUB), dim3(256), 0, stream>>>(cb, wsf, wsc2);

    hipFuncSetAttribute((const void*)pq_mfma4,
                        hipFuncAttributeMaxDynamicSharedMemorySize, LDS_TOTAL);
    const int nb = (nrows + ROWS_PER_BLK - 1) / ROWS_PER_BLK;   // 32
    pq_mfma4<<<dim3(nb * NSUB), dim3(256), LDS_TOTAL, stream>>>(
        emb, cb, wsf, wsc2, out, nrows);
}

// Round 7
// 294.583 us; speedup vs baseline: 22.8863x; 20.5934x over previous
//
#include <hip/hip_runtime.h>

typedef short   bf16x8 __attribute__((ext_vector_type(8)));
typedef unsigned short u16x4 __attribute__((ext_vector_type(4)));
typedef unsigned short u16x8 __attribute__((ext_vector_type(8)));
typedef float   f32x16 __attribute__((ext_vector_type(16)));

constexpr int NSUB  = 8;
constexpr int NCODE = 256;
constexpr int SDIM  = 96;
constexpr int EMB   = NSUB * SDIM;          // 768
constexpr int TILE_ROWS = 128;
constexpr int ROWS_PER_BLK = 1024;
constexpr int NTILES = ROWS_PER_BLK / TILE_ROWS;   // 8
constexpr float C_SHIFT = 192.0f;   // harmless positivity shift baked into c2 (cancels in gaps)
constexpr float THR = 0.02f;        // validated recheck trigger (rounds 2-3)

constexpr int    CB_UNITS      = 8 * 6 * 2 * 64;                 // 6144 x 16B per subspace
constexpr size_t WS_FRAG_BYTES = (size_t)NSUB * CB_UNITS * 16;   // 786432
constexpr size_t WS_NEEDED     = WS_FRAG_BYTES + (size_t)NSUB * NCODE * 4;

// ---- dynamic LDS layout (bytes) ----
constexpr int CB_OFF    = 0;                        // 98304 : codebook frags (one m)
constexpr int X_OFF     = 98304;                    // 49152 : x frags (128 rows)
constexpr int C2_OFF    = X_OFF + 49152;            // 1024  : 0.5||c||^2 + shift
constexpr int SB_OFF    = C2_OFF + 1024;            // 4096  : scanbuf [2][128] {b1,b2,i1,i2}
constexpr int BK_OFF    = SB_OFF + 4096;            // 512   : per-row best code
constexpr int LDS_TOTAL = BK_OFF + 512;             // 153088 <= 163840

__device__ __forceinline__ unsigned short f2bf(float v) {
    unsigned u = __builtin_bit_cast(unsigned, v);
    u = u + 0x7FFFu + ((u >> 16) & 1u);          // RNE
    return (unsigned short)(u >> 16);
}
__device__ __forceinline__ float bf2f(unsigned short h) {
    unsigned u = ((unsigned)h) << 16;
    return __builtin_bit_cast(float, u);
}

// X LDS swizzle: unit u (1 KiB), byte off in [0,1024): XOR bits 4..6 by (u&7).
// Reads (uniform u per instr, off=lane*16) conflict-free; writes spread banks.
__device__ __forceinline__ int xaddr(int u, int off) {
    return u * 1024 + (off ^ ((u & 7) << 4));
}

__device__ __forceinline__ void gll16(const void* g, void* lds) {
    __builtin_amdgcn_global_load_lds((const __attribute__((address_space(1))) unsigned int*)g,
                                     (__attribute__((address_space(3))) unsigned int*)lds, 16, 0, 0);
}
__device__ __forceinline__ void gll4(const void* g, void* lds) {
    __builtin_amdgcn_global_load_lds((const __attribute__((address_space(1))) unsigned int*)g,
                                     (__attribute__((address_space(3))) unsigned int*)lds, 4, 0, 0);
}

// ---------------- pre-kernel: pack codebook into ws (validated) ----------------
// frag unit u = ((t*6+s)*2+h)*64 + l : code=t*32+(l&31), k0=s*16+(l>>5)*8,
// value = h==0 ? hi : lo of (-cb). wsc2 = 0.5*||c||^2 + C_SHIFT (fp64).
__global__ __launch_bounds__(256) void pq_prep(const float* __restrict__ cb,
                                               unsigned short* __restrict__ wsf,
                                               float* __restrict__ wsc2)
{
    const int m   = (int)blockIdx.x;
    const int tid = (int)threadIdx.x;
    {
        const float* c = cb + ((size_t)m * NCODE + tid) * SDIM;
        double s = 0.0;
        for (int k = 0; k < SDIM; ++k) { double v = (double)c[k]; s += v * v; }
        wsc2[m * NCODE + tid] = (float)(0.5 * s + (double)C_SHIFT);
    }
    for (int i = 0; i < 24; ++i) {
        int u  = i * 256 + tid;
        int l  = u & 63;
        int c6 = u >> 6;
        int h  = c6 & 1; c6 >>= 1;
        int s  = c6 % 6;
        int t  = c6 / 6;
        int code = t * 32 + (l & 31);
        int k0   = s * 16 + (l >> 5) * 8;
        const float* src = cb + (size_t)m * NCODE * SDIM + (size_t)code * SDIM + k0;
        u16x8 o;
        #pragma unroll
        for (int j = 0; j < 8; ++j) {
            float v = -src[j];
            unsigned short hb = f2bf(v);
            o[j] = (h == 0) ? hb : f2bf(v - bf2f(hb));
        }
        *(u16x8*)(wsf + ((size_t)m * CB_UNITS + u) * 8) = o;
    }
}

// ------ main: 512 thr / 8 waves, cb staged ONCE per block, round-3 epilogue ------
__global__ __launch_bounds__(512) void pq_mfma5(
    const float* __restrict__ emb,
    const float* __restrict__ cb,
    const unsigned short* __restrict__ wsf,
    const float* __restrict__ wsc2,
    float* __restrict__ out,
    int nrows)
{
    extern __shared__ char smem[];
    const int tid   = (int)threadIdx.x;
    const int w     = tid >> 6;                 // 0..7
    const int lane  = tid & 63;
    const int hib   = lane >> 5;
    const int g     = w & 3;                    // row group (32 rows of the 128-tile)
    const int thalf = w >> 2;                   // code half (4 t-groups = 128 codes)
    const int m     = (int)(blockIdx.x & 7);
    const int chunk = (int)(blockIdx.x >> 3);
    const int row0  = chunk * ROWS_PER_BLK;

    float4* sb = (float4*)(smem + SB_OFF);      // [thalf][row] = {b1, b2, bits(i1), bits(i2)}
    int*    bk = (int*)(smem + BK_OFF);

    // ---- prologue: stage codebook frags + c2 ONCE (async) ----
    {
        const unsigned short* wb = wsf + (size_t)m * CB_UNITS * 8;
        #pragma unroll
        for (int i = 0; i < 12; ++i) {
            int sbu = (w * 12 + i) * 64;
            gll16(wb + (size_t)(sbu + lane) * 8, smem + CB_OFF + sbu * 16);
        }
        if (w < 4) gll4(wsc2 + m * NCODE + w * 64 + lane, smem + C2_OFF + w * 256);
    }

    float4 xf[6];
    auto issue_x = [&](int t) {
        #pragma unroll
        for (int ii = 0; ii < 6; ++ii) {
            int Q = ii * 512 + tid;             // 3072 quads = 128 rows x 24
            int r = Q / 24, f = Q % 24;
            int gr = row0 + t * TILE_ROWS + r;
            if (gr >= nrows) gr = nrows - 1;
            xf[ii] = *(const float4*)(emb + (size_t)gr * EMB + m * SDIM + f * 4);
        }
    };
    auto convert_x = [&]() {
        #pragma unroll
        for (int ii = 0; ii < 6; ++ii) {
            int Q = ii * 512 + tid;
            int r = Q / 24, f = Q % 24;
            int s = f >> 2, kh = (f >> 1) & 1, j0 = f & 1;
            int g2 = r >> 5, lp = (r & 31) + 32 * kh;
            float v[4] = { xf[ii].x, xf[ii].y, xf[ii].z, xf[ii].w };
            u16x4 hi4, lo4;
            #pragma unroll
            for (int e = 0; e < 4; ++e) {
                unsigned short hb = f2bf(v[e]);
                hi4[e] = hb;
                lo4[e] = f2bf(v[e] - bf2f(hb));
            }
            int uh  = (g2 * 6 + s) * 2;
            int off = lp * 16 + j0 * 8;
            *(u16x4*)(smem + X_OFF + xaddr(uh, off))     = hi4;
            *(u16x4*)(smem + X_OFF + xaddr(uh + 1, off)) = lo4;
        }
    };

    issue_x(0);
    convert_x();
    issue_x(1);
    __syncthreads();                    // drains gll staging + tile-0 X writes

    #pragma unroll 1
    for (int t = 0; t < NTILES; ++t) {
        const int rowt0 = row0 + t * TILE_ROWS;

        // ---- P2: MFMA (JIT x reads) + round-3-style serial-scan epilogue ----
        float b1 = 3.4e38f, b2 = 3.4e38f;
        int   i1 = 1 << 30, i2 = 1 << 30;
        #pragma unroll
        for (int pair = 0; pair < 2; ++pair) {
            const int t0 = thalf * 4 + pair * 2, t1 = t0 + 1;
            f32x16 a0, a1;
            {
                const float* c2p = (const float*)(smem + C2_OFF);
                #pragma unroll
                for (int rq = 0; rq < 4; ++rq) {
                    float4 q0 = *(const float4*)(c2p + t0 * 32 + rq * 8 + hib * 4);
                    float4 q1 = *(const float4*)(c2p + t1 * 32 + rq * 8 + hib * 4);
                    a0[rq*4+0]=q0.x; a0[rq*4+1]=q0.y; a0[rq*4+2]=q0.z; a0[rq*4+3]=q0.w;
                    a1[rq*4+0]=q1.x; a1[rq*4+1]=q1.y; a1[rq*4+2]=q1.z; a1[rq*4+3]=q1.w;
                }
            }
            const char* cbp = smem + CB_OFF;
            const char* xbp = smem + X_OFF;
            #pragma unroll
            for (int s = 0; s < 6; ++s) {       // pass 1: x-hi
                bf16x8 xh  = *(const bf16x8*)(xbp + xaddr((g * 6 + s) * 2, lane * 16));
                bf16x8 ah0 = *(const bf16x8*)(cbp + (((t0 * 6 + s) * 2 + 0) * 64 + lane) * 16);
                bf16x8 al0 = *(const bf16x8*)(cbp + (((t0 * 6 + s) * 2 + 1) * 64 + lane) * 16);
                bf16x8 ah1 = *(const bf16x8*)(cbp + (((t1 * 6 + s) * 2 + 0) * 64 + lane) * 16);
                bf16x8 al1 = *(const bf16x8*)(cbp + (((t1 * 6 + s) * 2 + 1) * 64 + lane) * 16);
                a0 = __builtin_amdgcn_mfma_f32_32x32x16_bf16(ah0, xh, a0, 0, 0, 0);
                a1 = __builtin_amdgcn_mfma_f32_32x32x16_bf16(ah1, xh, a1, 0, 0, 0);
                a0 = __builtin_amdgcn_mfma_f32_32x32x16_bf16(al0, xh, a0, 0, 0, 0);
                a1 = __builtin_amdgcn_mfma_f32_32x32x16_bf16(al1, xh, a1, 0, 0, 0);
            }
            #pragma unroll
            for (int s = 0; s < 6; ++s) {       // pass 2: x-lo (hi codebook only)
                bf16x8 xl  = *(const bf16x8*)(xbp + xaddr((g * 6 + s) * 2 + 1, lane * 16));
                bf16x8 ah0 = *(const bf16x8*)(cbp + (((t0 * 6 + s) * 2 + 0) * 64 + lane) * 16);
                bf16x8 ah1 = *(const bf16x8*)(cbp + (((t1 * 6 + s) * 2 + 0) * 64 + lane) * 16);
                a0 = __builtin_amdgcn_mfma_f32_32x32x16_bf16(ah0, xl, a0, 0, 0, 0);
                a1 = __builtin_amdgcn_mfma_f32_32x32x16_bf16(ah1, xl, a1, 0, 0, 0);
            }
            // serial scan, ascending code order per lane (first-min tie rule)
            #pragma unroll
            for (int r = 0; r < 16; ++r) {
                float sv = a0[r];
                int   kv = t0 * 32 + (r & 3) + 8 * (r >> 2) + hib * 4;
                if (sv < b1)      { b2 = b1; i2 = i1; b1 = sv; i1 = kv; }
                else if (sv < b2) { b2 = sv; i2 = kv; }
            }
            #pragma unroll
            for (int r = 0; r < 16; ++r) {
                float sv = a1[r];
                int   kv = t1 * 32 + (r & 3) + 8 * (r >> 2) + hib * 4;
                if (sv < b1)      { b2 = b1; i2 = i1; b1 = sv; i1 = kv; }
                else if (sv < b2) { b2 = sv; i2 = kv; }
            }
        }
        {   // merge lane^32 partner (same rows, other hib codes) — round-3 code
            float ob1 = __shfl_xor(b1, 32);
            int   oi1 = __shfl_xor(i1, 32);
            float ob2 = __shfl_xor(b2, 32);
            int   oi2 = __shfl_xor(i2, 32);
            bool o1_better = (ob1 < b1) || (ob1 == b1 && oi1 < i1);
            if (o1_better) {
                bool mine_better = (b1 < ob2) || (b1 == ob2 && i1 < oi2);
                if (mine_better) { b2 = b1; i2 = i1; } else { b2 = ob2; i2 = oi2; }
                b1 = ob1; i1 = oi1;
            } else {
                if ((ob1 < b2) || (ob1 == b2 && oi1 < i2)) { b2 = ob1; i2 = oi1; }
            }
        }
        if (lane < 32)
            sb[thalf * TILE_ROWS + g * 32 + lane] =
                make_float4(b1, b2, __builtin_bit_cast(float, i1), __builtin_bit_cast(float, i2));
        __syncthreads();                        // bar2: scanbuf ready

        // ---- P3: merge 2 halves + cheap top-2 fp64 recheck -> bk ----
        if (tid < TILE_ROWS) {
            int r = tid;
            float4 A = sb[r];                   // codes 0..127
            float4 B = sb[TILE_ROWS + r];       // codes 128..255
            float b1a = A.x, b2a = A.y; int i1a = __builtin_bit_cast(int, A.z), i2a = __builtin_bit_cast(int, A.w);
            float b1b = B.x, b2b = B.y; int i1b = __builtin_bit_cast(int, B.z), i2b = __builtin_bit_cast(int, B.w);
            // winner: strict < keeps A on tie (A codes are smaller) — numpy rule
            float w1; int wi1;
            float l1; int li1;                  // loser of the two bests
            if (b1b < b1a) { w1 = b1b; wi1 = i1b; l1 = b1a; li1 = i1a; }
            else           { w1 = b1a; wi1 = i1a; l1 = b1b; li1 = i1b; }
            // runner-up among {loser, b2a, b2b}, tie -> lower idx
            float w2 = l1; int wi2 = li1;
            if (b2a < w2 || (b2a == w2 && i2a < wi2)) { w2 = b2a; wi2 = i2a; }
            if (b2b < w2 || (b2b == w2 && i2b < wi2)) { w2 = b2b; wi2 = i2b; }
            int grow = rowt0 + r;
            if (grow < nrows) {
                if (w2 - w1 < THR) {            // exact fp64 top-2 recheck (validated)
                    const float* xr = emb + (size_t)grow * EMB + m * SDIM;
                    const float* ca = cb + ((size_t)m * NCODE + wi1) * SDIM;
                    const float* cbv = cb + ((size_t)m * NCODE + wi2) * SDIM;
                    double da = 0.0, db = 0.0;
                    for (int kk = 0; kk < SDIM; ++kk) {
                        double ea = (double)xr[kk] - (double)ca[kk];
                        double eb = (double)xr[kk] - (double)cbv[kk];
                        da += ea * ea; db += eb * eb;
                    }
                    if (db < da || (db == da && wi2 < wi1)) wi1 = wi2;
                }
                bk[r] = wi1;
            }
        }
        __syncthreads();                        // bar3: bk final, X consumed

        // ---- P4: gather-write tile t; convert tile t+1; prefetch t+2 ----
        if (t + 1 < NTILES) { convert_x(); issue_x(t + 2); }
        {
            #pragma unroll
            for (int ii = 0; ii < 6; ++ii) {
                int Q = ii * 512 + tid;
                int r = Q / 24, f = Q % 24;
                int grow = rowt0 + r;
                if (grow < nrows) {
                    int k = bk[r];
                    float4 v = *(const float4*)(cb + ((size_t)m * NCODE + k) * SDIM + f * 4);
                    *(float4*)(out + (size_t)grow * EMB + m * SDIM + f * 4) = v;
                }
            }
        }
        __syncthreads();                        // bar1(next): X(t+1) ready, bk consumed
    }
}

// ---------------- fallback (round-2 kernel, validated) ----------------
__global__ __launch_bounds__(256) void pq_argmin_kernel(
    const float* __restrict__ emb, const float* __restrict__ cb,
    float* __restrict__ out, int nrows)
{
    const int m   = (int)(blockIdx.x & 7);
    const int row = (int)(blockIdx.x >> 3) * 256 + (int)threadIdx.x;
    const float* __restrict__ cbm = cb + (size_t)m * (NCODE * SDIM);
    __shared__ float half_c2[NCODE];
    {
        const int k = (int)threadIdx.x;
        const float* c = cbm + k * SDIM;
        float s = 0.f;
        #pragma unroll
        for (int i = 0; i < SDIM; i += 4) {
            const float4 v = *reinterpret_cast<const float4*>(c + i);
            s = fmaf(v.x, v.x, s); s = fmaf(v.y, v.y, s);
            s = fmaf(v.z, v.z, s); s = fmaf(v.w, v.w, s);
        }
        half_c2[k] = 0.5f * s;
    }
    __syncthreads();
    if (row >= nrows) return;
    float x[SDIM];
    {
        const float* xr = emb + (size_t)row * EMB + m * SDIM;
        #pragma unroll
        for (int i = 0; i < SDIM; i += 4) {
            const float4 v = *reinterpret_cast<const float4*>(xr + i);
            x[i+0] = v.x; x[i+1] = v.y; x[i+2] = v.z; x[i+3] = v.w;
        }
    }
    float best = 3.4e38f, best2 = 3.4e38f;
    int bestk = 0, bestk2 = 0;
    #pragma unroll 1
    for (int k = 0; k < NCODE; k += 4) {
        const float* c0 = cbm + (k + 0) * SDIM;
        const float* c1 = cbm + (k + 1) * SDIM;
        const float* c2 = cbm + (k + 2) * SDIM;
        const float* c3 = cbm + (k + 3) * SDIM;
        float a0 = 0.f, a1 = 0.f, a2 = 0.f, a3 = 0.f;
        #pragma unroll
        for (int i = 0; i < SDIM; i += 4) {
            const float4 v0 = *reinterpret_cast<const float4*>(c0 + i);
            const float4 v1 = *reinterpret_cast<const float4*>(c1 + i);
            const float4 v2 = *reinterpret_cast<const float4*>(c2 + i);
            const float4 v3 = *reinterpret_cast<const float4*>(c3 + i);
            a0 = fmaf(x[i+0], v0.x, a0); a0 = fmaf(x[i+1], v0.y, a0);
            a0 = fmaf(x[i+2], v0.z, a0); a0 = fmaf(x[i+3], v0.w, a0);
            a1 = fmaf(x[i+0], v1.x, a1); a1 = fmaf(x[i+1], v1.y, a1);
            a1 = fmaf(x[i+2], v1.z, a1); a1 = fmaf(x[i+3], v1.w, a1);
            a2 = fmaf(x[i+0], v2.x, a2); a2 = fmaf(x[i+1], v2.y, a2);
            a2 = fmaf(x[i+2], v2.z, a2); a2 = fmaf(x[i+3], v2.w, a2);
            a3 = fmaf(x[i+0], v3.x, a3); a3 = fmaf(x[i+1], v3.y, a3);
            a3 = fmaf(x[i+2], v3.z, a3); a3 = fmaf(x[i+3], v3.w, a3);
        }
        const float s[4] = { half_c2[k+0] - a0, half_c2[k+1] - a1,
                             half_c2[k+2] - a2, half_c2[k+3] - a3 };
        #pragma unroll
        for (int j = 0; j < 4; ++j) {
            if (s[j] < best)       { best2 = best; bestk2 = bestk; best = s[j]; bestk = k + j; }
            else if (s[j] < best2) { best2 = s[j]; bestk2 = k + j; }
        }
    }
    if (best2 - best < 0.02f) {
        const float* ca = cbm + bestk  * SDIM;
        const float* cbv = cbm + bestk2 * SDIM;
        double da = 0.0, db = 0.0;
        for (int i = 0; i < SDIM; ++i) {
            const double ea = (double)x[i] - (double)ca[i];
            const double eb = (double)x[i] - (double)cbv[i];
            da += ea * ea; db += eb * eb;
        }
        if (db < da || (db == da && bestk2 < bestk)) bestk = bestk2;
    }
    const float* cbest = cbm + bestk * SDIM;
    float* o = out + (size_t)row * EMB + m * SDIM;
    #pragma unroll
    for (int i = 0; i < SDIM; i += 4)
        *reinterpret_cast<float4*>(o + i) = *reinterpret_cast<const float4*>(cbest + i);
}

extern "C" void kernel_launch(void* const* d_in, const int* in_sizes, int n_in,
                              void* d_out, int out_size, void* d_ws, size_t ws_size,
                              hipStream_t stream) {
    const float* emb = (const float*)d_in[0];
    const float* cb  = (const float*)d_in[1];
    float* out = (float*)d_out;
    const int nrows = in_sizes[0] / EMB;    // 65536

    if (ws_size < WS_NEEDED) {
        const int rowBlocks = (nrows + 255) / 256;
        pq_argmin_kernel<<<dim3(rowBlocks * NSUB), dim3(256), 0, stream>>>(emb, cb, out, nrows);
        return;
    }

    unsigned short* wsf = (unsigned short*)d_ws;
    float* wsc2 = (float*)((char*)d_ws + WS_FRAG_BYTES);

    pq_prep<<<dim3(NSUB), dim3(256), 0, stream>>>(cb, wsf, wsc2);

    hipFuncSetAttribute((const void*)pq_mfma5,
                        hipFuncAttributeMaxDynamicSharedMemorySize, LDS_TOTAL);
    const int nb = (nrows + ROWS_PER_BLK - 1) / ROWS_PER_BLK;   // 64
    pq_mfma5<<<dim3(nb * NSUB), dim3(512), LDS_TOTAL, stream>>>(
        emb, cb, wsf, wsc2, out, nrows);
}

// Round 8
// 254.733 us; speedup vs baseline: 26.4665x; 1.1564x over previous
//
#include <hip/hip_runtime.h>

typedef short   bf16x8 __attribute__((ext_vector_type(8)));
typedef unsigned short u16x4 __attribute__((ext_vector_type(4)));
typedef unsigned short u16x8 __attribute__((ext_vector_type(8)));
typedef float   f32x16 __attribute__((ext_vector_type(16)));

constexpr int NSUB  = 8;
constexpr int NCODE = 256;
constexpr int SDIM  = 96;
constexpr int EMB   = NSUB * SDIM;          // 768
constexpr int TILE_ROWS = 64;
constexpr int ROWS_PER_BLK = 1024;
constexpr int NTILES = ROWS_PER_BLK / TILE_ROWS;   // 16
constexpr float C_SHIFT = 192.0f;   // harmless positivity shift baked into c2 (cancels in gaps)
constexpr float THR = 0.02f;        // validated recheck trigger (rounds 2-3-7)

constexpr int    CB_UNITS      = 8 * 6 * 2 * 64;                 // 6144 x 16B per subspace
constexpr size_t WS_FRAG_BYTES = (size_t)NSUB * CB_UNITS * 16;   // 786432
constexpr size_t WS_NEEDED     = WS_FRAG_BYTES + (size_t)NSUB * NCODE * 4;

// ---- dynamic LDS layout (bytes) — 77.3 KB => 2 blocks/CU ----
constexpr int CB_OFF    = 0;                        // 49152 : cb HI frags only (48 units)
constexpr int X_OFF     = 49152;                    // 24576 : x frags (64 rows, 24 units)
constexpr int C2_OFF    = X_OFF + 24576;            // 1024  : 0.5||c||^2 + shift
constexpr int SB_OFF    = C2_OFF + 1024;            // 4096  : scanbuf [4][64] {b1,b2,i1,i2}
constexpr int BK_OFF    = SB_OFF + 4096;            // 256   : per-row best code
constexpr int LDS_TOTAL = BK_OFF + 256;             // 79104 -> 2 blocks/CU

__device__ __forceinline__ unsigned short f2bf(float v) {
    unsigned u = __builtin_bit_cast(unsigned, v);
    u = u + 0x7FFFu + ((u >> 16) & 1u);          // RNE
    return (unsigned short)(u >> 16);
}
__device__ __forceinline__ float bf2f(unsigned short h) {
    unsigned u = ((unsigned)h) << 16;
    return __builtin_bit_cast(float, u);
}

// X LDS swizzle: unit u (1 KiB), byte off in [0,1024): XOR bits 4..6 by (u&7).
// Reads (uniform u per instr, off=lane*16) conflict-free; writes spread banks.
__device__ __forceinline__ int xaddr(int u, int off) {
    return u * 1024 + (off ^ ((u & 7) << 4));
}

__device__ __forceinline__ void gll16(const void* g, void* lds) {
    __builtin_amdgcn_global_load_lds((const __attribute__((address_space(1))) unsigned int*)g,
                                     (__attribute__((address_space(3))) unsigned int*)lds, 16, 0, 0);
}
__device__ __forceinline__ void gll4(const void* g, void* lds) {
    __builtin_amdgcn_global_load_lds((const __attribute__((address_space(1))) unsigned int*)g,
                                     (__attribute__((address_space(3))) unsigned int*)lds, 4, 0, 0);
}

// ---------------- pre-kernel: pack codebook into ws (validated) ----------------
// frag unit u = ((t*6+s)*2+h)*64 + l : code=t*32+(l&31), k0=s*16+(l>>5)*8,
// value = h==0 ? hi : lo of (-cb). wsc2 = 0.5*||c||^2 + C_SHIFT (fp64).
__global__ __launch_bounds__(256) void pq_prep(const float* __restrict__ cb,
                                               unsigned short* __restrict__ wsf,
                                               float* __restrict__ wsc2)
{
    const int m   = (int)blockIdx.x;
    const int tid = (int)threadIdx.x;
    {
        const float* c = cb + ((size_t)m * NCODE + tid) * SDIM;
        double s = 0.0;
        for (int k = 0; k < SDIM; ++k) { double v = (double)c[k]; s += v * v; }
        wsc2[m * NCODE + tid] = (float)(0.5 * s + (double)C_SHIFT);
    }
    for (int i = 0; i < 24; ++i) {
        int u  = i * 256 + tid;
        int l  = u & 63;
        int c6 = u >> 6;
        int h  = c6 & 1; c6 >>= 1;
        int s  = c6 % 6;
        int t  = c6 / 6;
        int code = t * 32 + (l & 31);
        int k0   = s * 16 + (l >> 5) * 8;
        const float* src = cb + (size_t)m * NCODE * SDIM + (size_t)code * SDIM + k0;
        u16x8 o;
        #pragma unroll
        for (int j = 0; j < 8; ++j) {
            float v = -src[j];
            unsigned short hb = f2bf(v);
            o[j] = (h == 0) ? hb : f2bf(v - bf2f(hb));
        }
        *(u16x8*)(wsf + ((size_t)m * CB_UNITS + u) * 8) = o;
    }
}

// ------ main: 512 thr / 8 waves = 2 row-groups x 4 code-quarters; ------
// ------ cb-HI in LDS (once), cb-LO streamed from L2; 2 blocks/CU  ------
__global__ __launch_bounds__(512) void pq_mfma6(
    const float* __restrict__ emb,
    const float* __restrict__ cb,
    const unsigned short* __restrict__ wsf,
    const float* __restrict__ wsc2,
    float* __restrict__ out,
    int nrows)
{
    extern __shared__ char smem[];
    const int tid   = (int)threadIdx.x;
    const int w     = tid >> 6;                 // 0..7
    const int lane  = tid & 63;
    const int hib   = lane >> 5;
    const int g     = w & 1;                    // row group (32 rows of the 64-tile)
    const int tq    = w >> 1;                   // code quarter (2 t-groups = 64 codes)
    const int m     = (int)(blockIdx.x & 7);
    const int chunk = (int)(blockIdx.x >> 3);
    const int row0  = chunk * ROWS_PER_BLK;

    float4* sb = (float4*)(smem + SB_OFF);      // [tq][row] = {b1, b2, bits(i1), bits(i2)}
    int*    bk = (int*)(smem + BK_OFF);

    const unsigned short* wb = wsf + (size_t)m * CB_UNITS * 8;

    // ---- prologue: stage cb-HI frags + c2 ONCE (async) ----
    {
        #pragma unroll
        for (int i = 0; i < 6; ++i) {
            int u = w * 6 + i;                  // LDS hi unit (t*6+s), u in [0,48)
            gll16(wb + (size_t)(u * 2 * 64 + lane) * 8, smem + CB_OFF + u * 1024 + lane * 16);
        }
        if (w < 4) gll4(wsc2 + m * NCODE + w * 64 + lane, smem + C2_OFF + w * 256);
    }

    float4 xf[3];
    auto issue_x = [&](int t) {
        #pragma unroll
        for (int ii = 0; ii < 3; ++ii) {
            int Q = ii * 512 + tid;             // 1536 quads = 64 rows x 24
            int r = Q / 24, f = Q % 24;
            int gr = row0 + t * TILE_ROWS + r;
            if (gr >= nrows) gr = nrows - 1;
            xf[ii] = *(const float4*)(emb + (size_t)gr * EMB + m * SDIM + f * 4);
        }
    };
    auto convert_x = [&]() {
        #pragma unroll
        for (int ii = 0; ii < 3; ++ii) {
            int Q = ii * 512 + tid;
            int r = Q / 24, f = Q % 24;
            int s = f >> 2, kh = (f >> 1) & 1, j0 = f & 1;
            int g2 = r >> 5, lp = (r & 31) + 32 * kh;
            float v[4] = { xf[ii].x, xf[ii].y, xf[ii].z, xf[ii].w };
            u16x4 hi4, lo4;
            #pragma unroll
            for (int e = 0; e < 4; ++e) {
                unsigned short hb = f2bf(v[e]);
                hi4[e] = hb;
                lo4[e] = f2bf(v[e] - bf2f(hb));
            }
            int uh  = (g2 * 6 + s) * 2;
            int off = lp * 16 + j0 * 8;
            *(u16x4*)(smem + X_OFF + xaddr(uh, off))     = hi4;
            *(u16x4*)(smem + X_OFF + xaddr(uh + 1, off)) = lo4;
        }
    };

    issue_x(0);
    convert_x();
    issue_x(1);
    __syncthreads();                    // drains gll staging + tile-0 X writes

    #pragma unroll 1
    for (int t = 0; t < NTILES; ++t) {
        const int rowt0 = row0 + t * TILE_ROWS;

        // ---- P2: MFMA (cb-hi LDS, cb-lo global/L2, x JIT) + serial-scan epilogue ----
        const int t0 = tq * 2, t1 = t0 + 1;
        f32x16 a0, a1;
        {
            const float* c2p = (const float*)(smem + C2_OFF);
            #pragma unroll
            for (int rq = 0; rq < 4; ++rq) {
                float4 q0 = *(const float4*)(c2p + t0 * 32 + rq * 8 + hib * 4);
                float4 q1 = *(const float4*)(c2p + t1 * 32 + rq * 8 + hib * 4);
                a0[rq*4+0]=q0.x; a0[rq*4+1]=q0.y; a0[rq*4+2]=q0.z; a0[rq*4+3]=q0.w;
                a1[rq*4+0]=q1.x; a1[rq*4+1]=q1.y; a1[rq*4+2]=q1.z; a1[rq*4+3]=q1.w;
            }
        }
        {
            const char* cbp = smem + CB_OFF;
            const char* xbp = smem + X_OFF;
            #pragma unroll
            for (int s = 0; s < 6; ++s) {
                bf16x8 xh  = *(const bf16x8*)(xbp + xaddr((g * 6 + s) * 2,     lane * 16));
                bf16x8 xl  = *(const bf16x8*)(xbp + xaddr((g * 6 + s) * 2 + 1, lane * 16));
                bf16x8 ah0 = *(const bf16x8*)(cbp + ((t0 * 6 + s) * 64 + lane) * 16);
                bf16x8 ah1 = *(const bf16x8*)(cbp + ((t1 * 6 + s) * 64 + lane) * 16);
                bf16x8 al0 = *(const bf16x8*)(wb + (size_t)((((t0 * 6 + s) * 2) + 1) * 64 + lane) * 8);
                bf16x8 al1 = *(const bf16x8*)(wb + (size_t)((((t1 * 6 + s) * 2) + 1) * 64 + lane) * 8);
                a0 = __builtin_amdgcn_mfma_f32_32x32x16_bf16(ah0, xh, a0, 0, 0, 0);
                a1 = __builtin_amdgcn_mfma_f32_32x32x16_bf16(ah1, xh, a1, 0, 0, 0);
                a0 = __builtin_amdgcn_mfma_f32_32x32x16_bf16(al0, xh, a0, 0, 0, 0);
                a1 = __builtin_amdgcn_mfma_f32_32x32x16_bf16(al1, xh, a1, 0, 0, 0);
                a0 = __builtin_amdgcn_mfma_f32_32x32x16_bf16(ah0, xl, a0, 0, 0, 0);
                a1 = __builtin_amdgcn_mfma_f32_32x32x16_bf16(ah1, xl, a1, 0, 0, 0);
            }
        }
        // serial scan, ascending code order per lane (first-min tie rule)
        float b1 = 3.4e38f, b2 = 3.4e38f;
        int   i1 = 1 << 30, i2 = 1 << 30;
        #pragma unroll
        for (int r = 0; r < 16; ++r) {
            float sv = a0[r];
            int   kv = t0 * 32 + (r & 3) + 8 * (r >> 2) + hib * 4;
            if (sv < b1)      { b2 = b1; i2 = i1; b1 = sv; i1 = kv; }
            else if (sv < b2) { b2 = sv; i2 = kv; }
        }
        #pragma unroll
        for (int r = 0; r < 16; ++r) {
            float sv = a1[r];
            int   kv = t1 * 32 + (r & 3) + 8 * (r >> 2) + hib * 4;
            if (sv < b1)      { b2 = b1; i2 = i1; b1 = sv; i1 = kv; }
            else if (sv < b2) { b2 = sv; i2 = kv; }
        }
        {   // merge lane^32 partner (same rows, other hib codes) — validated code
            float ob1 = __shfl_xor(b1, 32);
            int   oi1 = __shfl_xor(i1, 32);
            float ob2 = __shfl_xor(b2, 32);
            int   oi2 = __shfl_xor(i2, 32);
            bool o1_better = (ob1 < b1) || (ob1 == b1 && oi1 < i1);
            if (o1_better) {
                bool mine_better = (b1 < ob2) || (b1 == ob2 && i1 < oi2);
                if (mine_better) { b2 = b1; i2 = i1; } else { b2 = ob2; i2 = oi2; }
                b1 = ob1; i1 = oi1;
            } else {
                if ((ob1 < b2) || (ob1 == b2 && oi1 < i2)) { b2 = ob1; i2 = oi1; }
            }
        }
        if (lane < 32)
            sb[tq * TILE_ROWS + g * 32 + lane] =
                make_float4(b1, b2, __builtin_bit_cast(float, i1), __builtin_bit_cast(float, i2));
        __syncthreads();                        // bar2: scanbuf ready

        // ---- P3: merge 4 quarters (code-ascending) + cheap top-2 fp64 recheck ----
        if (tid < TILE_ROWS) {
            int r = tid;
            float4 A = sb[r];
            float mb1 = A.x, mb2 = A.y;
            int   mi1 = __builtin_bit_cast(int, A.z), mi2 = __builtin_bit_cast(int, A.w);
            #pragma unroll
            for (int q = 1; q < 4; ++q) {
                float4 B = sb[q * TILE_ROWS + r];
                float q1 = B.x, q2 = B.y;
                int   qi1 = __builtin_bit_cast(int, B.z), qi2 = __builtin_bit_cast(int, B.w);
                if (q1 < mb1)      { mb2 = mb1; mi2 = mi1; mb1 = q1; mi1 = qi1; }
                else if (q1 < mb2) { mb2 = q1;  mi2 = qi1; }
                if (q2 < mb2)      { mb2 = q2;  mi2 = qi2; }
            }
            int grow = rowt0 + r;
            if (grow < nrows) {
                if (mb2 - mb1 < THR) {          // exact fp64 top-2 recheck (validated)
                    const float* xr = emb + (size_t)grow * EMB + m * SDIM;
                    const float* ca = cb + ((size_t)m * NCODE + mi1) * SDIM;
                    const float* cbv = cb + ((size_t)m * NCODE + mi2) * SDIM;
                    double da = 0.0, db = 0.0;
                    for (int kk = 0; kk < SDIM; ++kk) {
                        double ea = (double)xr[kk] - (double)ca[kk];
                        double eb = (double)xr[kk] - (double)cbv[kk];
                        da += ea * ea; db += eb * eb;
                    }
                    if (db < da || (db == da && mi2 < mi1)) mi1 = mi2;
                }
                bk[r] = mi1;
            }
        }
        __syncthreads();                        // bar3: bk final, X(t) consumed

        // ---- P4: convert tile t+1 into X; prefetch t+2; gather-write tile t ----
        if (t + 1 < NTILES) { convert_x(); issue_x(t + 2); }
        {
            #pragma unroll
            for (int ii = 0; ii < 3; ++ii) {
                int Q = ii * 512 + tid;
                int r = Q / 24, f = Q % 24;
                int grow = rowt0 + r;
                if (grow < nrows) {
                    int k = bk[r];
                    float4 v = *(const float4*)(cb + ((size_t)m * NCODE + k) * SDIM + f * 4);
                    *(float4*)(out + (size_t)grow * EMB + m * SDIM + f * 4) = v;
                }
            }
        }
        __syncthreads();                        // bar1(next): X(t+1) ready, bk consumed
    }
}

// ---------------- fallback (round-2 kernel, validated) ----------------
__global__ __launch_bounds__(256) void pq_argmin_kernel(
    const float* __restrict__ emb, const float* __restrict__ cb,
    float* __restrict__ out, int nrows)
{
    const int m   = (int)(blockIdx.x & 7);
    const int row = (int)(blockIdx.x >> 3) * 256 + (int)threadIdx.x;
    const float* __restrict__ cbm = cb + (size_t)m * (NCODE * SDIM);
    __shared__ float half_c2[NCODE];
    {
        const int k = (int)threadIdx.x;
        const float* c = cbm + k * SDIM;
        float s = 0.f;
        #pragma unroll
        for (int i = 0; i < SDIM; i += 4) {
            const float4 v = *reinterpret_cast<const float4*>(c + i);
            s = fmaf(v.x, v.x, s); s = fmaf(v.y, v.y, s);
            s = fmaf(v.z, v.z, s); s = fmaf(v.w, v.w, s);
        }
        half_c2[k] = 0.5f * s;
    }
    __syncthreads();
    if (row >= nrows) return;
    float x[SDIM];
    {
        const float* xr = emb + (size_t)row * EMB + m * SDIM;
        #pragma unroll
        for (int i = 0; i < SDIM; i += 4) {
            const float4 v = *reinterpret_cast<const float4*>(xr + i);
            x[i+0] = v.x; x[i+1] = v.y; x[i+2] = v.z; x[i+3] = v.w;
        }
    }
    float best = 3.4e38f, best2 = 3.4e38f;
    int bestk = 0, bestk2 = 0;
    #pragma unroll 1
    for (int k = 0; k < NCODE; k += 4) {
        const float* c0 = cbm + (k + 0) * SDIM;
        const float* c1 = cbm + (k + 1) * SDIM;
        const float* c2 = cbm + (k + 2) * SDIM;
        const float* c3 = cbm + (k + 3) * SDIM;
        float a0 = 0.f, a1 = 0.f, a2 = 0.f, a3 = 0.f;
        #pragma unroll
        for (int i = 0; i < SDIM; i += 4) {
            const float4 v0 = *reinterpret_cast<const float4*>(c0 + i);
            const float4 v1 = *reinterpret_cast<const float4*>(c1 + i);
            const float4 v2 = *reinterpret_cast<const float4*>(c2 + i);
            const float4 v3 = *reinterpret_cast<const float4*>(c3 + i);
            a0 = fmaf(x[i+0], v0.x, a0); a0 = fmaf(x[i+1], v0.y, a0);
            a0 = fmaf(x[i+2], v0.z, a0); a0 = fmaf(x[i+3], v0.w, a0);
            a1 = fmaf(x[i+0], v1.x, a1); a1 = fmaf(x[i+1], v1.y, a1);
            a1 = fmaf(x[i+2], v1.z, a1); a1 = fmaf(x[i+3], v1.w, a1);
            a2 = fmaf(x[i+0], v2.x, a2); a2 = fmaf(x[i+1], v2.y, a2);
            a2 = fmaf(x[i+2], v2.z, a2); a2 = fmaf(x[i+3], v2.w, a2);
            a3 = fmaf(x[i+0], v3.x, a3); a3 = fmaf(x[i+1], v3.y, a3);
            a3 = fmaf(x[i+2], v3.z, a3); a3 = fmaf(x[i+3], v3.w, a3);
        }
        const float s[4] = { half_c2[k+0] - a0, half_c2[k+1] - a1,
                             half_c2[k+2] - a2, half_c2[k+3] - a3 };
        #pragma unroll
        for (int j = 0; j < 4; ++j) {
            if (s[j] < best)       { best2 = best; bestk2 = bestk; best = s[j]; bestk = k + j; }
            else if (s[j] < best2) { best2 = s[j]; bestk2 = k + j; }
        }
    }
    if (best2 - best < 0.02f) {
        const float* ca = cbm + bestk  * SDIM;
        const float* cbv = cbm + bestk2 * SDIM;
        double da = 0.0, db = 0.0;
        for (int i = 0; i < SDIM; ++i) {
            const double ea = (double)x[i] - (double)ca[i];
            const double eb = (double)x[i] - (double)cbv[i];
            da += ea * ea; db += eb * eb;
        }
        if (db < da || (db == da && bestk2 < bestk)) bestk = bestk2;
    }
    const float* cbest = cbm + bestk * SDIM;
    float* o = out + (size_t)row * EMB + m * SDIM;
    #pragma unroll
    for (int i = 0; i < SDIM; i += 4)
        *reinterpret_cast<float4*>(o + i) = *reinterpret_cast<const float4*>(cbest + i);
}

extern "C" void kernel_launch(void* const* d_in, const int* in_sizes, int n_in,
                              void* d_out, int out_size, void* d_ws, size_t ws_size,
                              hipStream_t stream) {
    const float* emb = (const float*)d_in[0];
    const float* cb  = (const float*)d_in[1];
    float* out = (float*)d_out;
    const int nrows = in_sizes[0] / EMB;    // 65536

    if (ws_size < WS_NEEDED) {
        const int rowBlocks = (nrows + 255) / 256;
        pq_argmin_kernel<<<dim3(rowBlocks * NSUB), dim3(256), 0, stream>>>(emb, cb, out, nrows);
        return;
    }

    unsigned short* wsf = (unsigned short*)d_ws;
    float* wsc2 = (float*)((char*)d_ws + WS_FRAG_BYTES);

    pq_prep<<<dim3(NSUB), dim3(256), 0, stream>>>(cb, wsf, wsc2);

    hipFuncSetAttribute((const void*)pq_mfma6,
                        hipFuncAttributeMaxDynamicSharedMemorySize, LDS_TOTAL);
    const int nb = (nrows + ROWS_PER_BLK - 1) / ROWS_PER_BLK;   // 64
    pq_mfma6<<<dim3(nb * NSUB), dim3(512), LDS_TOTAL, stream>>>(
        emb, cb, wsf, wsc2, out, nrows);
}

// Round 9
// 236.717 us; speedup vs baseline: 28.4809x; 1.0761x over previous
//
#include <hip/hip_runtime.h>

typedef short   bf16x8 __attribute__((ext_vector_type(8)));
typedef unsigned short u16x4 __attribute__((ext_vector_type(4)));
typedef unsigned short u16x8 __attribute__((ext_vector_type(8)));
typedef float   f32x16 __attribute__((ext_vector_type(16)));

constexpr int NSUB  = 8;
constexpr int NCODE = 256;
constexpr int SDIM  = 96;
constexpr int EMB   = NSUB * SDIM;          // 768
constexpr int TILE_ROWS = 64;
constexpr int ROWS_PER_BLK = 512;
constexpr int NTILES = ROWS_PER_BLK / TILE_ROWS;   // 8
constexpr float C_SHIFT = 192.0f;   // harmless positivity shift baked into c2 (cancels in gaps)
constexpr float THR = 0.02f;        // validated recheck trigger (rounds 2-3-7-8)

constexpr int    CB_UNITS      = 8 * 6 * 2 * 64;                 // 6144 x 16B per subspace
constexpr size_t WS_FRAG_BYTES = (size_t)NSUB * CB_UNITS * 16;   // 786432
constexpr size_t WS_NEEDED     = WS_FRAG_BYTES + (size_t)NSUB * NCODE * 4;

// ---- dynamic LDS layout (bytes) — 29.3 KB => 4 blocks/CU (wave-capped) ----
constexpr int X_OFF     = 0;                        // 24576 : x frags (64 rows, 24 units)
constexpr int C2_OFF    = X_OFF + 24576;            // 1024  : 0.5||c||^2 + shift
constexpr int SB_OFF    = C2_OFF + 1024;            // 4096  : scanbuf [4][64] {b1,b2,i1,i2}
constexpr int BK_OFF    = SB_OFF + 4096;            // 256   : per-row best code
constexpr int LDS_TOTAL = BK_OFF + 256;             // 29952

__device__ __forceinline__ unsigned short f2bf(float v) {
    unsigned u = __builtin_bit_cast(unsigned, v);
    u = u + 0x7FFFu + ((u >> 16) & 1u);          // RNE
    return (unsigned short)(u >> 16);
}
__device__ __forceinline__ float bf2f(unsigned short h) {
    unsigned u = ((unsigned)h) << 16;
    return __builtin_bit_cast(float, u);
}

// X LDS swizzle: unit u (1 KiB), byte off in [0,1024): XOR bits 4..6 by (u&7).
// Reads (uniform u per instr, off=lane*16) conflict-free; writes spread banks.
__device__ __forceinline__ int xaddr(int u, int off) {
    return u * 1024 + (off ^ ((u & 7) << 4));
}

__device__ __forceinline__ void gll4(const void* g, void* lds) {
    __builtin_amdgcn_global_load_lds((const __attribute__((address_space(1))) unsigned int*)g,
                                     (__attribute__((address_space(3))) unsigned int*)lds, 4, 0, 0);
}

// ---------------- pre-kernel: pack codebook into ws (validated) ----------------
// frag unit u = ((t*6+s)*2+h)*64 + l : code=t*32+(l&31), k0=s*16+(l>>5)*8,
// value = h==0 ? hi : lo of (-cb). wsc2 = 0.5*||c||^2 + C_SHIFT (fp64).
__global__ __launch_bounds__(256) void pq_prep(const float* __restrict__ cb,
                                               unsigned short* __restrict__ wsf,
                                               float* __restrict__ wsc2)
{
    const int m   = (int)blockIdx.x;
    const int tid = (int)threadIdx.x;
    {
        const float* c = cb + ((size_t)m * NCODE + tid) * SDIM;
        double s = 0.0;
        for (int k = 0; k < SDIM; ++k) { double v = (double)c[k]; s += v * v; }
        wsc2[m * NCODE + tid] = (float)(0.5 * s + (double)C_SHIFT);
    }
    for (int i = 0; i < 24; ++i) {
        int u  = i * 256 + tid;
        int l  = u & 63;
        int c6 = u >> 6;
        int h  = c6 & 1; c6 >>= 1;
        int s  = c6 % 6;
        int t  = c6 / 6;
        int code = t * 32 + (l & 31);
        int k0   = s * 16 + (l >> 5) * 8;
        const float* src = cb + (size_t)m * NCODE * SDIM + (size_t)code * SDIM + k0;
        u16x8 o;
        #pragma unroll
        for (int j = 0; j < 8; ++j) {
            float v = -src[j];
            unsigned short hb = f2bf(v);
            o[j] = (h == 0) ? hb : f2bf(v - bf2f(hb));
        }
        *(u16x8*)(wsf + ((size_t)m * CB_UNITS + u) * 8) = o;
    }
}

// ------ main: 512 thr / 8 waves = 2 row-groups x 4 code-quarters;      ------
// ------ cb streamed ENTIRELY from L2 (coalesced 1KB/wave); 4 blocks/CU ------
__global__ __launch_bounds__(512) void pq_mfma7(
    const float* __restrict__ emb,
    const float* __restrict__ cb,
    const unsigned short* __restrict__ wsf,
    const float* __restrict__ wsc2,
    float* __restrict__ out,
    int nrows)
{
    extern __shared__ char smem[];
    const int tid   = (int)threadIdx.x;
    const int w     = tid >> 6;                 // 0..7
    const int lane  = tid & 63;
    const int hib   = lane >> 5;
    const int g     = w & 1;                    // row group (32 rows of the 64-tile)
    const int tq    = w >> 1;                   // code quarter (2 t-groups = 64 codes)
    const int m     = (int)(blockIdx.x & 7);
    const int chunk = (int)(blockIdx.x >> 3);
    const int row0  = chunk * ROWS_PER_BLK;

    float4* sb = (float4*)(smem + SB_OFF);      // [tq][row] = {b1, b2, bits(i1), bits(i2)}
    int*    bk = (int*)(smem + BK_OFF);

    const unsigned short* wb = wsf + (size_t)m * CB_UNITS * 8;

    // ---- prologue: stage c2 (async, tiny) ----
    if (w < 4) gll4(wsc2 + m * NCODE + w * 64 + lane, smem + C2_OFF + w * 256);

    float4 xf[3];
    auto issue_x = [&](int t) {
        #pragma unroll
        for (int ii = 0; ii < 3; ++ii) {
            int Q = ii * 512 + tid;             // 1536 quads = 64 rows x 24
            int r = Q / 24, f = Q % 24;
            int gr = row0 + t * TILE_ROWS + r;
            if (gr >= nrows) gr = nrows - 1;
            xf[ii] = *(const float4*)(emb + (size_t)gr * EMB + m * SDIM + f * 4);
        }
    };
    auto convert_x = [&]() {
        #pragma unroll
        for (int ii = 0; ii < 3; ++ii) {
            int Q = ii * 512 + tid;
            int r = Q / 24, f = Q % 24;
            int s = f >> 2, kh = (f >> 1) & 1, j0 = f & 1;
            int g2 = r >> 5, lp = (r & 31) + 32 * kh;
            float v[4] = { xf[ii].x, xf[ii].y, xf[ii].z, xf[ii].w };
            u16x4 hi4, lo4;
            #pragma unroll
            for (int e = 0; e < 4; ++e) {
                unsigned short hb = f2bf(v[e]);
                hi4[e] = hb;
                lo4[e] = f2bf(v[e] - bf2f(hb));
            }
            int uh  = (g2 * 6 + s) * 2;
            int off = lp * 16 + j0 * 8;
            *(u16x4*)(smem + X_OFF + xaddr(uh, off))     = hi4;
            *(u16x4*)(smem + X_OFF + xaddr(uh + 1, off)) = lo4;
        }
    };

    issue_x(0);
    convert_x();
    issue_x(1);
    __syncthreads();                    // drains gll c2 + tile-0 X writes

    #pragma unroll 1
    for (int t = 0; t < NTILES; ++t) {
        const int rowt0 = row0 + t * TILE_ROWS;

        // ---- P2: MFMA (cb hi+lo streamed from L2, x JIT from LDS) + serial scan ----
        const int t0 = tq * 2, t1 = t0 + 1;
        f32x16 a0, a1;
        {
            const float* c2p = (const float*)(smem + C2_OFF);
            #pragma unroll
            for (int rq = 0; rq < 4; ++rq) {
                float4 q0 = *(const float4*)(c2p + t0 * 32 + rq * 8 + hib * 4);
                float4 q1 = *(const float4*)(c2p + t1 * 32 + rq * 8 + hib * 4);
                a0[rq*4+0]=q0.x; a0[rq*4+1]=q0.y; a0[rq*4+2]=q0.z; a0[rq*4+3]=q0.w;
                a1[rq*4+0]=q1.x; a1[rq*4+1]=q1.y; a1[rq*4+2]=q1.z; a1[rq*4+3]=q1.w;
            }
        }
        {
            const char* xbp = smem + X_OFF;
            #pragma unroll
            for (int s = 0; s < 6; ++s) {
                bf16x8 xh  = *(const bf16x8*)(xbp + xaddr((g * 6 + s) * 2,     lane * 16));
                bf16x8 xl  = *(const bf16x8*)(xbp + xaddr((g * 6 + s) * 2 + 1, lane * 16));
                bf16x8 ah0 = *(const bf16x8*)(wb + (size_t)((((t0 * 6 + s) * 2) + 0) * 64 + lane) * 8);
                bf16x8 al0 = *(const bf16x8*)(wb + (size_t)((((t0 * 6 + s) * 2) + 1) * 64 + lane) * 8);
                bf16x8 ah1 = *(const bf16x8*)(wb + (size_t)((((t1 * 6 + s) * 2) + 0) * 64 + lane) * 8);
                bf16x8 al1 = *(const bf16x8*)(wb + (size_t)((((t1 * 6 + s) * 2) + 1) * 64 + lane) * 8);
                a0 = __builtin_amdgcn_mfma_f32_32x32x16_bf16(ah0, xh, a0, 0, 0, 0);
                a1 = __builtin_amdgcn_mfma_f32_32x32x16_bf16(ah1, xh, a1, 0, 0, 0);
                a0 = __builtin_amdgcn_mfma_f32_32x32x16_bf16(al0, xh, a0, 0, 0, 0);
                a1 = __builtin_amdgcn_mfma_f32_32x32x16_bf16(al1, xh, a1, 0, 0, 0);
                a0 = __builtin_amdgcn_mfma_f32_32x32x16_bf16(ah0, xl, a0, 0, 0, 0);
                a1 = __builtin_amdgcn_mfma_f32_32x32x16_bf16(ah1, xl, a1, 0, 0, 0);
            }
        }
        // serial scan, ascending code order per lane (first-min tie rule)
        float b1 = 3.4e38f, b2 = 3.4e38f;
        int   i1 = 1 << 30, i2 = 1 << 30;
        #pragma unroll
        for (int r = 0; r < 16; ++r) {
            float sv = a0[r];
            int   kv = t0 * 32 + (r & 3) + 8 * (r >> 2) + hib * 4;
            if (sv < b1)      { b2 = b1; i2 = i1; b1 = sv; i1 = kv; }
            else if (sv < b2) { b2 = sv; i2 = kv; }
        }
        #pragma unroll
        for (int r = 0; r < 16; ++r) {
            float sv = a1[r];
            int   kv = t1 * 32 + (r & 3) + 8 * (r >> 2) + hib * 4;
            if (sv < b1)      { b2 = b1; i2 = i1; b1 = sv; i1 = kv; }
            else if (sv < b2) { b2 = sv; i2 = kv; }
        }
        {   // merge lane^32 partner (same rows, other hib codes) — validated code
            float ob1 = __shfl_xor(b1, 32);
            int   oi1 = __shfl_xor(i1, 32);
            float ob2 = __shfl_xor(b2, 32);
            int   oi2 = __shfl_xor(i2, 32);
            bool o1_better = (ob1 < b1) || (ob1 == b1 && oi1 < i1);
            if (o1_better) {
                bool mine_better = (b1 < ob2) || (b1 == ob2 && i1 < oi2);
                if (mine_better) { b2 = b1; i2 = i1; } else { b2 = ob2; i2 = oi2; }
                b1 = ob1; i1 = oi1;
            } else {
                if ((ob1 < b2) || (ob1 == b2 && oi1 < i2)) { b2 = ob1; i2 = oi1; }
            }
        }
        if (lane < 32)
            sb[tq * TILE_ROWS + g * 32 + lane] =
                make_float4(b1, b2, __builtin_bit_cast(float, i1), __builtin_bit_cast(float, i2));
        __syncthreads();                        // bar2: scanbuf ready

        // ---- P3: merge 4 quarters (code-ascending) + cheap top-2 fp64 recheck ----
        if (tid < TILE_ROWS) {
            int r = tid;
            float4 A = sb[r];
            float mb1 = A.x, mb2 = A.y;
            int   mi1 = __builtin_bit_cast(int, A.z), mi2 = __builtin_bit_cast(int, A.w);
            #pragma unroll
            for (int q = 1; q < 4; ++q) {
                float4 B = sb[q * TILE_ROWS + r];
                float q1 = B.x, q2 = B.y;
                int   qi1 = __builtin_bit_cast(int, B.z), qi2 = __builtin_bit_cast(int, B.w);
                if (q1 < mb1)      { mb2 = mb1; mi2 = mi1; mb1 = q1; mi1 = qi1; }
                else if (q1 < mb2) { mb2 = q1;  mi2 = qi1; }
                if (q2 < mb2)      { mb2 = q2;  mi2 = qi2; }
            }
            int grow = rowt0 + r;
            if (grow < nrows) {
                if (mb2 - mb1 < THR) {          // exact fp64 top-2 recheck (validated)
                    const float* xr = emb + (size_t)grow * EMB + m * SDIM;
                    const float* ca = cb + ((size_t)m * NCODE + mi1) * SDIM;
                    const float* cbv = cb + ((size_t)m * NCODE + mi2) * SDIM;
                    double da = 0.0, db = 0.0;
                    for (int kk = 0; kk < SDIM; ++kk) {
                        double ea = (double)xr[kk] - (double)ca[kk];
                        double eb = (double)xr[kk] - (double)cbv[kk];
                        da += ea * ea; db += eb * eb;
                    }
                    if (db < da || (db == da && mi2 < mi1)) mi1 = mi2;
                }
                bk[r] = mi1;
            }
        }
        __syncthreads();                        // bar3: bk final, X(t) consumed

        // ---- P4: convert tile t+1 into X; prefetch t+2; gather-write tile t ----
        if (t + 1 < NTILES) { convert_x(); issue_x(t + 2); }
        {
            #pragma unroll
            for (int ii = 0; ii < 3; ++ii) {
                int Q = ii * 512 + tid;
                int r = Q / 24, f = Q % 24;
                int grow = rowt0 + r;
                if (grow < nrows) {
                    int k = bk[r];
                    float4 v = *(const float4*)(cb + ((size_t)m * NCODE + k) * SDIM + f * 4);
                    *(float4*)(out + (size_t)grow * EMB + m * SDIM + f * 4) = v;
                }
            }
        }
        __syncthreads();                        // bar1(next): X(t+1) ready, bk consumed
    }
}

// ---------------- fallback (round-2 kernel, validated) ----------------
__global__ __launch_bounds__(256) void pq_argmin_kernel(
    const float* __restrict__ emb, const float* __restrict__ cb,
    float* __restrict__ out, int nrows)
{
    const int m   = (int)(blockIdx.x & 7);
    const int row = (int)(blockIdx.x >> 3) * 256 + (int)threadIdx.x;
    const float* __restrict__ cbm = cb + (size_t)m * (NCODE * SDIM);
    __shared__ float half_c2[NCODE];
    {
        const int k = (int)threadIdx.x;
        const float* c = cbm + k * SDIM;
        float s = 0.f;
        #pragma unroll
        for (int i = 0; i < SDIM; i += 4) {
            const float4 v = *reinterpret_cast<const float4*>(c + i);
            s = fmaf(v.x, v.x, s); s = fmaf(v.y, v.y, s);
            s = fmaf(v.z, v.z, s); s = fmaf(v.w, v.w, s);
        }
        half_c2[k] = 0.5f * s;
    }
    __syncthreads();
    if (row >= nrows) return;
    float x[SDIM];
    {
        const float* xr = emb + (size_t)row * EMB + m * SDIM;
        #pragma unroll
        for (int i = 0; i < SDIM; i += 4) {
            const float4 v = *reinterpret_cast<const float4*>(xr + i);
            x[i+0] = v.x; x[i+1] = v.y; x[i+2] = v.z; x[i+3] = v.w;
        }
    }
    float best = 3.4e38f, best2 = 3.4e38f;
    int bestk = 0, bestk2 = 0;
    #pragma unroll 1
    for (int k = 0; k < NCODE; k += 4) {
        const float* c0 = cbm + (k + 0) * SDIM;
        const float* c1 = cbm + (k + 1) * SDIM;
        const float* c2 = cbm + (k + 2) * SDIM;
        const float* c3 = cbm + (k + 3) * SDIM;
        float a0 = 0.f, a1 = 0.f, a2 = 0.f, a3 = 0.f;
        #pragma unroll
        for (int i = 0; i < SDIM; i += 4) {
            const float4 v0 = *reinterpret_cast<const float4*>(c0 + i);
            const float4 v1 = *reinterpret_cast<const float4*>(c1 + i);
            const float4 v2 = *reinterpret_cast<const float4*>(c2 + i);
            const float4 v3 = *reinterpret_cast<const float4*>(c3 + i);
            a0 = fmaf(x[i+0], v0.x, a0); a0 = fmaf(x[i+1], v0.y, a0);
            a0 = fmaf(x[i+2], v0.z, a0); a0 = fmaf(x[i+3], v0.w, a0);
            a1 = fmaf(x[i+0], v1.x, a1); a1 = fmaf(x[i+1], v1.y, a1);
            a1 = fmaf(x[i+2], v1.z, a1); a1 = fmaf(x[i+3], v1.w, a1);
            a2 = fmaf(x[i+0], v2.x, a2); a2 = fmaf(x[i+1], v2.y, a2);
            a2 = fmaf(x[i+2], v2.z, a2); a2 = fmaf(x[i+3], v2.w, a2);
            a3 = fmaf(x[i+0], v3.x, a3); a3 = fmaf(x[i+1], v3.y, a3);
            a3 = fmaf(x[i+2], v3.z, a3); a3 = fmaf(x[i+3], v3.w, a3);
        }
        const float s[4] = { half_c2[k+0] - a0, half_c2[k+1] - a1,
                             half_c2[k+2] - a2, half_c2[k+3] - a3 };
        #pragma unroll
        for (int j = 0; j < 4; ++j) {
            if (s[j] < best)       { best2 = best; bestk2 = bestk; best = s[j]; bestk = k + j; }
            else if (s[j] < best2) { best2 = s[j]; bestk2 = k + j; }
        }
    }
    if (best2 - best < 0.02f) {
        const float* ca = cbm + bestk  * SDIM;
        const float* cbv = cbm + bestk2 * SDIM;
        double da = 0.0, db = 0.0;
        for (int i = 0; i < SDIM; ++i) {
            const double ea = (double)x[i] - (double)ca[i];
            const double eb = (double)x[i] - (double)cbv[i];
            da += ea * ea; db += eb * eb;
        }
        if (db < da || (db == da && bestk2 < bestk)) bestk = bestk2;
    }
    const float* cbest = cbm + bestk * SDIM;
    float* o = out + (size_t)row * EMB + m * SDIM;
    #pragma unroll
    for (int i = 0; i < SDIM; i += 4)
        *reinterpret_cast<float4*>(o + i) = *reinterpret_cast<const float4*>(cbest + i);
}

extern "C" void kernel_launch(void* const* d_in, const int* in_sizes, int n_in,
                              void* d_out, int out_size, void* d_ws, size_t ws_size,
                              hipStream_t stream) {
    const float* emb = (const float*)d_in[0];
    const float* cb  = (const float*)d_in[1];
    float* out = (float*)d_out;
    const int nrows = in_sizes[0] / EMB;    // 65536

    if (ws_size < WS_NEEDED) {
        const int rowBlocks = (nrows + 255) / 256;
        pq_argmin_kernel<<<dim3(rowBlocks * NSUB), dim3(256), 0, stream>>>(emb, cb, out, nrows);
        return;
    }

    unsigned short* wsf = (unsigned short*)d_ws;
    float* wsc2 = (float*)((char*)d_ws + WS_FRAG_BYTES);

    pq_prep<<<dim3(NSUB), dim3(256), 0, stream>>>(cb, wsf, wsc2);

    hipFuncSetAttribute((const void*)pq_mfma7,
                        hipFuncAttributeMaxDynamicSharedMemorySize, LDS_TOTAL);
    const int nb = (nrows + ROWS_PER_BLK - 1) / ROWS_PER_BLK;   // 128
    pq_mfma7<<<dim3(nb * NSUB), dim3(512), LDS_TOTAL, stream>>>(
        emb, cb, wsf, wsc2, out, nrows);
}

// Round 10
// 206.247 us; speedup vs baseline: 32.6885x; 1.1477x over previous
//
#include <hip/hip_runtime.h>

typedef short   bf16x8 __attribute__((ext_vector_type(8)));
typedef unsigned short u16x8 __attribute__((ext_vector_type(8)));
typedef float   f32x16 __attribute__((ext_vector_type(16)));

constexpr int NSUB  = 8;
constexpr int NCODE = 256;
constexpr int SDIM  = 96;
constexpr int EMB   = NSUB * SDIM;          // 768
constexpr float C_SHIFT = 192.0f;   // harmless positivity shift baked into c2 (cancels in gaps)
constexpr float THR = 0.02f;        // validated recheck trigger (rounds 2-3-7-8-9)

constexpr int    CB_UNITS      = 8 * 6 * 2 * 64;                 // 6144 x 16B per subspace
constexpr size_t WS_FRAG_BYTES = (size_t)NSUB * CB_UNITS * 16;   // 786432
constexpr size_t WS_NEEDED     = WS_FRAG_BYTES + (size_t)NSUB * NCODE * 4;

__device__ __forceinline__ unsigned short f2bf(float v) {
    unsigned u = __builtin_bit_cast(unsigned, v);
    u = u + 0x7FFFu + ((u >> 16) & 1u);          // RNE
    return (unsigned short)(u >> 16);
}
__device__ __forceinline__ float bf2f(unsigned short h) {
    unsigned u = ((unsigned)h) << 16;
    return __builtin_bit_cast(float, u);
}

// ---------------- pre-kernel: pack codebook into ws (validated) ----------------
// frag unit u = ((t*6+s)*2+h)*64 + l : code=t*32+(l&31), k0=s*16+(l>>5)*8,
// value = h==0 ? hi : lo of (-cb). wsc2 = 0.5*||c||^2 + C_SHIFT (fp64).
__global__ __launch_bounds__(256) void pq_prep(const float* __restrict__ cb,
                                               unsigned short* __restrict__ wsf,
                                               float* __restrict__ wsc2)
{
    const int m   = (int)blockIdx.x;
    const int tid = (int)threadIdx.x;
    {
        const float* c = cb + ((size_t)m * NCODE + tid) * SDIM;
        double s = 0.0;
        for (int k = 0; k < SDIM; ++k) { double v = (double)c[k]; s += v * v; }
        wsc2[m * NCODE + tid] = (float)(0.5 * s + (double)C_SHIFT);
    }
    for (int i = 0; i < 24; ++i) {
        int u  = i * 256 + tid;
        int l  = u & 63;
        int c6 = u >> 6;
        int h  = c6 & 1; c6 >>= 1;
        int s  = c6 % 6;
        int t  = c6 / 6;
        int code = t * 32 + (l & 31);
        int k0   = s * 16 + (l >> 5) * 8;
        const float* src = cb + (size_t)m * NCODE * SDIM + (size_t)code * SDIM + k0;
        u16x8 o;
        #pragma unroll
        for (int j = 0; j < 8; ++j) {
            float v = -src[j];
            unsigned short hb = f2bf(v);
            o[j] = (h == 0) ? hb : f2bf(v - bf2f(hb));
        }
        *(u16x8*)(wsf + ((size_t)m * CB_UNITS + u) * 8) = o;
    }
}

// ------ main: one wave owns (m, 32 rows). NO LDS, NO barriers.           ------
// ------ x in registers; cb hi/lo + c2 streamed from L2-resident ws.      ------
__global__ __launch_bounds__(256, 3) void pq_mfma8(
    const float* __restrict__ emb,
    const float* __restrict__ cb,
    const unsigned short* __restrict__ wsf,
    const float* __restrict__ wsc2,
    float* __restrict__ out,
    int nrows,
    int rowblks)
{
    const int tid  = (int)threadIdx.x;
    const int lane = tid & 63;
    const int hib  = lane >> 5;
    const int widx = (int)blockIdx.x * 4 + (tid >> 6);
    if (widx >= NSUB * rowblks) return;
    const int m    = widx / rowblks;            // waves of one m are contiguous
    const int rb   = widx % rowblks;
    const int row0 = rb * 32;

    const unsigned short* wb = wsf + (size_t)m * CB_UNITS * 8;
    const float* c2p = wsc2 + m * NCODE;

    // ---- load this lane's x fragments straight from emb; hi/lo split in regs ----
    // lane l holds row (l&31), dims s*16 + (l>>5)*8 + [0..8)  (validated B layout)
    bf16x8 xh[6], xl[6];
    {
        int r = row0 + (lane & 31);
        if (r >= nrows) r = nrows - 1;
        const float* xr = emb + (size_t)r * EMB + m * SDIM + hib * 8;
        #pragma unroll
        for (int s = 0; s < 6; ++s) {
            float4 v0 = *(const float4*)(xr + s * 16);
            float4 v1 = *(const float4*)(xr + s * 16 + 4);
            float v[8] = { v0.x, v0.y, v0.z, v0.w, v1.x, v1.y, v1.z, v1.w };
            #pragma unroll
            for (int j = 0; j < 8; ++j) {
                unsigned short hb = f2bf(v[j]);
                xh[s][j] = (short)hb;
                xl[s][j] = (short)f2bf(v[j] - bf2f(hb));
            }
        }
    }

    // ---- 4 t-pairs: acc init from c2, 36 MFMA, serial scan (code-ascending) ----
    float b1 = 3.4e38f, b2 = 3.4e38f;
    int   i1 = 1 << 30, i2 = 1 << 30;
    #pragma unroll 1
    for (int p = 0; p < 4; ++p) {
        const int t0 = p * 2, t1 = t0 + 1;
        f32x16 a0, a1;
        #pragma unroll
        for (int rq = 0; rq < 4; ++rq) {
            float4 q0 = *(const float4*)(c2p + t0 * 32 + rq * 8 + hib * 4);
            float4 q1 = *(const float4*)(c2p + t1 * 32 + rq * 8 + hib * 4);
            a0[rq*4+0]=q0.x; a0[rq*4+1]=q0.y; a0[rq*4+2]=q0.z; a0[rq*4+3]=q0.w;
            a1[rq*4+0]=q1.x; a1[rq*4+1]=q1.y; a1[rq*4+2]=q1.z; a1[rq*4+3]=q1.w;
        }
        #pragma unroll
        for (int s = 0; s < 6; ++s) {
            bf16x8 ah0 = *(const bf16x8*)(wb + (size_t)((((t0 * 6 + s) * 2) + 0) * 64 + lane) * 8);
            bf16x8 al0 = *(const bf16x8*)(wb + (size_t)((((t0 * 6 + s) * 2) + 1) * 64 + lane) * 8);
            bf16x8 ah1 = *(const bf16x8*)(wb + (size_t)((((t1 * 6 + s) * 2) + 0) * 64 + lane) * 8);
            bf16x8 al1 = *(const bf16x8*)(wb + (size_t)((((t1 * 6 + s) * 2) + 1) * 64 + lane) * 8);
            a0 = __builtin_amdgcn_mfma_f32_32x32x16_bf16(ah0, xh[s], a0, 0, 0, 0);
            a1 = __builtin_amdgcn_mfma_f32_32x32x16_bf16(ah1, xh[s], a1, 0, 0, 0);
            a0 = __builtin_amdgcn_mfma_f32_32x32x16_bf16(al0, xh[s], a0, 0, 0, 0);
            a1 = __builtin_amdgcn_mfma_f32_32x32x16_bf16(al1, xh[s], a1, 0, 0, 0);
            a0 = __builtin_amdgcn_mfma_f32_32x32x16_bf16(ah0, xl[s], a0, 0, 0, 0);
            a1 = __builtin_amdgcn_mfma_f32_32x32x16_bf16(ah1, xl[s], a1, 0, 0, 0);
        }
        // serial scan, ascending code order per lane (first-min tie rule)
        #pragma unroll
        for (int r = 0; r < 16; ++r) {
            float sv = a0[r];
            int   kv = t0 * 32 + (r & 3) + 8 * (r >> 2) + hib * 4;
            if (sv < b1)      { b2 = b1; i2 = i1; b1 = sv; i1 = kv; }
            else if (sv < b2) { b2 = sv; i2 = kv; }
        }
        #pragma unroll
        for (int r = 0; r < 16; ++r) {
            float sv = a1[r];
            int   kv = t1 * 32 + (r & 3) + 8 * (r >> 2) + hib * 4;
            if (sv < b1)      { b2 = b1; i2 = i1; b1 = sv; i1 = kv; }
            else if (sv < b2) { b2 = sv; i2 = kv; }
        }
    }
    {   // merge lane^32 partner (same rows, other hib codes) — validated code
        float ob1 = __shfl_xor(b1, 32);
        int   oi1 = __shfl_xor(i1, 32);
        float ob2 = __shfl_xor(b2, 32);
        int   oi2 = __shfl_xor(i2, 32);
        bool o1_better = (ob1 < b1) || (ob1 == b1 && oi1 < i1);
        if (o1_better) {
            bool mine_better = (b1 < ob2) || (b1 == ob2 && i1 < oi2);
            if (mine_better) { b2 = b1; i2 = i1; } else { b2 = ob2; i2 = oi2; }
            b1 = ob1; i1 = oi1;
        } else {
            if ((ob1 < b2) || (ob1 == b2 && oi1 < i2)) { b2 = ob1; i2 = oi1; }
        }
    }

    // ---- cheap top-2 fp64 recheck (validated; ~1% trigger; uniform 96-iter loop) ----
    {
        int grow = row0 + (lane & 31);
        if (lane < 32 && grow < nrows && (b2 - b1 < THR)) {
            const float* xr = emb + (size_t)grow * EMB + m * SDIM;
            const float* ca = cb + ((size_t)m * NCODE + i1) * SDIM;
            const float* cbv = cb + ((size_t)m * NCODE + i2) * SDIM;
            double da = 0.0, db = 0.0;
            for (int kk = 0; kk < SDIM; ++kk) {
                double ea = (double)xr[kk] - (double)ca[kk];
                double eb = (double)xr[kk] - (double)cbv[kk];
                da += ea * ea; db += eb * eb;
            }
            if (db < da || (db == da && i2 < i1)) i1 = i2;
        }
    }

    // ---- gather + coalesced write-out (24 lanes = 384B runs per row) ----
    #pragma unroll
    for (int ii = 0; ii < 12; ++ii) {
        int Q = ii * 64 + lane;                 // 768 = 32 rows x 24 float4
        int r = Q / 24, f = Q % 24;
        int grow = row0 + r;
        int k = __shfl(i1, r);                  // winner held by lane r (<32)
        if (grow < nrows) {
            float4 v = *(const float4*)(cb + ((size_t)m * NCODE + k) * SDIM + f * 4);
            *(float4*)(out + (size_t)grow * EMB + m * SDIM + f * 4) = v;
        }
    }
}

// ---------------- fallback (round-2 kernel, validated) ----------------
__global__ __launch_bounds__(256) void pq_argmin_kernel(
    const float* __restrict__ emb, const float* __restrict__ cb,
    float* __restrict__ out, int nrows)
{
    const int m   = (int)(blockIdx.x & 7);
    const int row = (int)(blockIdx.x >> 3) * 256 + (int)threadIdx.x;
    const float* __restrict__ cbm = cb + (size_t)m * (NCODE * SDIM);
    __shared__ float half_c2[NCODE];
    {
        const int k = (int)threadIdx.x;
        const float* c = cbm + k * SDIM;
        float s = 0.f;
        #pragma unroll
        for (int i = 0; i < SDIM; i += 4) {
            const float4 v = *reinterpret_cast<const float4*>(c + i);
            s = fmaf(v.x, v.x, s); s = fmaf(v.y, v.y, s);
            s = fmaf(v.z, v.z, s); s = fmaf(v.w, v.w, s);
        }
        half_c2[k] = 0.5f * s;
    }
    __syncthreads();
    if (row >= nrows) return;
    float x[SDIM];
    {
        const float* xr = emb + (size_t)row * EMB + m * SDIM;
        #pragma unroll
        for (int i = 0; i < SDIM; i += 4) {
            const float4 v = *reinterpret_cast<const float4*>(xr + i);
            x[i+0] = v.x; x[i+1] = v.y; x[i+2] = v.z; x[i+3] = v.w;
        }
    }
    float best = 3.4e38f, best2 = 3.4e38f;
    int bestk = 0, bestk2 = 0;
    #pragma unroll 1
    for (int k = 0; k < NCODE; k += 4) {
        const float* c0 = cbm + (k + 0) * SDIM;
        const float* c1 = cbm + (k + 1) * SDIM;
        const float* c2 = cbm + (k + 2) * SDIM;
        const float* c3 = cbm + (k + 3) * SDIM;
        float a0 = 0.f, a1 = 0.f, a2 = 0.f, a3 = 0.f;
        #pragma unroll
        for (int i = 0; i < SDIM; i += 4) {
            const float4 v0 = *reinterpret_cast<const float4*>(c0 + i);
            const float4 v1 = *reinterpret_cast<const float4*>(c1 + i);
            const float4 v2 = *reinterpret_cast<const float4*>(c2 + i);
            const float4 v3 = *reinterpret_cast<const float4*>(c3 + i);
            a0 = fmaf(x[i+0], v0.x, a0); a0 = fmaf(x[i+1], v0.y, a0);
            a0 = fmaf(x[i+2], v0.z, a0); a0 = fmaf(x[i+3], v0.w, a0);
            a1 = fmaf(x[i+0], v1.x, a1); a1 = fmaf(x[i+1], v1.y, a1);
            a1 = fmaf(x[i+2], v1.z, a1); a1 = fmaf(x[i+3], v1.w, a1);
            a2 = fmaf(x[i+0], v2.x, a2); a2 = fmaf(x[i+1], v2.y, a2);
            a2 = fmaf(x[i+2], v2.z, a2); a2 = fmaf(x[i+3], v2.w, a2);
            a3 = fmaf(x[i+0], v3.x, a3); a3 = fmaf(x[i+1], v3.y, a3);
            a3 = fmaf(x[i+2], v3.z, a3); a3 = fmaf(x[i+3], v3.w, a3);
        }
        const float s[4] = { half_c2[k+0] - a0, half_c2[k+1] - a1,
                             half_c2[k+2] - a2, half_c2[k+3] - a3 };
        #pragma unroll
        for (int j = 0; j < 4; ++j) {
            if (s[j] < best)       { best2 = best; bestk2 = bestk; best = s[j]; bestk = k + j; }
            else if (s[j] < best2) { best2 = s[j]; bestk2 = k + j; }
        }
    }
    if (best2 - best < 0.02f) {
        const float* ca = cbm + bestk  * SDIM;
        const float* cbv = cbm + bestk2 * SDIM;
        double da = 0.0, db = 0.0;
        for (int i = 0; i < SDIM; ++i) {
            const double ea = (double)x[i] - (double)ca[i];
            const double eb = (double)x[i] - (double)cbv[i];
            da += ea * ea; db += eb * eb;
        }
        if (db < da || (db == da && bestk2 < bestk)) bestk = bestk2;
    }
    const float* cbest = cbm + bestk * SDIM;
    float* o = out + (size_t)row * EMB + m * SDIM;
    #pragma unroll
    for (int i = 0; i < SDIM; i += 4)
        *reinterpret_cast<float4*>(o + i) = *reinterpret_cast<const float4*>(cbest + i);
}

extern "C" void kernel_launch(void* const* d_in, const int* in_sizes, int n_in,
                              void* d_out, int out_size, void* d_ws, size_t ws_size,
                              hipStream_t stream) {
    const float* emb = (const float*)d_in[0];
    const float* cb  = (const float*)d_in[1];
    float* out = (float*)d_out;
    const int nrows = in_sizes[0] / EMB;    // 65536

    if (ws_size < WS_NEEDED) {
        const int rowBlocks = (nrows + 255) / 256;
        pq_argmin_kernel<<<dim3(rowBlocks * NSUB), dim3(256), 0, stream>>>(emb, cb, out, nrows);
        return;
    }

    unsigned short* wsf = (unsigned short*)d_ws;
    float* wsc2 = (float*)((char*)d_ws + WS_FRAG_BYTES);

    pq_prep<<<dim3(NSUB), dim3(256), 0, stream>>>(cb, wsf, wsc2);

    const int rowblks = (nrows + 31) / 32;              // 2048
    const int nwaves  = rowblks * NSUB;                 // 16384
    const int nb      = (nwaves + 3) / 4;               // 4096 blocks of 256
    pq_mfma8<<<dim3(nb), dim3(256), 0, stream>>>(emb, cb, wsf, wsc2, out, nrows, rowblks);
}